// Round 1
// baseline (4513.501 us; speedup 1.0000x reference)
//
#include <hip/hip_runtime.h>

// ---- problem constants ----
constexpr int kN   = 20000;
constexpr int kE   = 160000;
constexpr int kR   = 3;
constexpr int kL   = 2;
constexpr int kIN  = 64;
constexpr int kHID = 128;
constexpr int kH   = 16;
constexpr int kFH  = 8;
constexpr int kHD2 = 64;

// ---- float atomic-max encoding (monotonic unsigned) ----
__device__ __forceinline__ unsigned fenc(float f) {
  unsigned u = __float_as_uint(f);
  return (u & 0x80000000u) ? ~u : (u | 0x80000000u);
}
__device__ __forceinline__ float fdec(unsigned e) {
  unsigned u = (e & 0x80000000u) ? (e & 0x7fffffffu) : ~e;
  return __uint_as_float(u);
}

// ---- generic GEMM: C[n,m] = A[n,k] @ W[k,m] (+bias) (+res) ----
__global__ void gemm_kernel(const float* __restrict__ A, const float* __restrict__ W,
                            const float* __restrict__ bias, const float* __restrict__ res,
                            float* __restrict__ C, int n, int k, int m) {
  int idx = blockIdx.x * 256 + threadIdx.x;
  if (idx >= n * m) return;
  int row = idx / m;
  int col = idx - row * m;
  const float* a = A + (size_t)row * k;
  float acc = bias ? bias[col] : 0.0f;
#pragma unroll 4
  for (int i = 0; i < k; i++) acc = fmaf(a[i], W[(size_t)i * m + col], acc);
  if (res) acc += res[idx];
  C[idx] = acc;
}

// ---- BatchNorm batch statistics: one block per column ----
__global__ void bn_stats_kernel(const float* __restrict__ X, int n, int m,
                                float* __restrict__ mean, float* __restrict__ var) {
  int c = blockIdx.x;
  float s = 0.f, s2 = 0.f;
  for (int i = threadIdx.x; i < n; i += 256) {
    float v = X[(size_t)i * m + c];
    s += v; s2 += v * v;
  }
  __shared__ float sh[256], sh2[256];
  sh[threadIdx.x] = s; sh2[threadIdx.x] = s2;
  __syncthreads();
  for (int off = 128; off > 0; off >>= 1) {
    if (threadIdx.x < off) { sh[threadIdx.x] += sh[threadIdx.x + off]; sh2[threadIdx.x] += sh2[threadIdx.x + off]; }
    __syncthreads();
  }
  if (threadIdx.x == 0) {
    float mu = sh[0] / n;
    mean[c] = mu;
    var[c] = sh2[0] / n - mu * mu;
  }
}

// ---- BN apply + ReLU ----
__global__ void bn_relu_kernel(const float* __restrict__ X, const float* __restrict__ mean,
                               const float* __restrict__ var, const float* __restrict__ g,
                               const float* __restrict__ bt, float* __restrict__ Y,
                               int total, int m) {
  int idx = blockIdx.x * 256 + threadIdx.x;
  if (idx >= total) return;
  int c = idx % m;
  float y = g[c] * (X[idx] - mean[c]) * rsqrtf(var[c] + 1e-5f) + bt[c];
  Y[idx] = fmaxf(y, 0.f);
}

// ---- per-node per-head attention logits: el/er ----
__global__ void eler_kernel(const float* __restrict__ z, const float* __restrict__ al,
                            const float* __restrict__ ar, float* __restrict__ el,
                            float* __restrict__ er) {
  int idx = blockIdx.x * 256 + threadIdx.x;
  if (idx >= kN * kH) return;
  int n = idx >> 4, hh = idx & 15;
  const float* zp = z + (size_t)n * kHID + hh * kFH;
  float sl = 0.f, sr = 0.f;
#pragma unroll
  for (int f = 0; f < kFH; f++) { float zv = zp[f]; sl += zv * al[hh * kFH + f]; sr += zv * ar[hh * kFH + f]; }
  el[idx] = sl; er[idx] = sr;
}

// ---- edge pass 1: segment max over dst ----
__global__ void edge_max_kernel(const int* __restrict__ src, const int* __restrict__ dst,
                                const float* __restrict__ el, const float* __restrict__ er,
                                unsigned* __restrict__ menc) {
  int idx = blockIdx.x * 256 + threadIdx.x;
  if (idx >= kE * kH) return;
  int e = idx >> 4, hh = idx & 15;
  int s = src[e], d = dst[e];
  float v = el[s * kH + hh] + er[d * kH + hh];
  v = v > 0.f ? v : 0.2f * v;
  atomicMax(&menc[d * kH + hh], fenc(v));
}

// ---- edge pass 2: exp and segment sum ----
__global__ void edge_expsum_kernel(const int* __restrict__ src, const int* __restrict__ dst,
                                   const float* __restrict__ el, const float* __restrict__ er,
                                   const unsigned* __restrict__ menc, float* __restrict__ exs,
                                   float* __restrict__ ssum) {
  int idx = blockIdx.x * 256 + threadIdx.x;
  if (idx >= kE * kH) return;
  int e = idx >> 4, hh = idx & 15;
  int s = src[e], d = dst[e];
  float v = el[s * kH + hh] + er[d * kH + hh];
  v = v > 0.f ? v : 0.2f * v;
  float mm = fdec(menc[d * kH + hh]);
  float ex = expf(v - mm);
  exs[idx] = ex;
  atomicAdd(&ssum[d * kH + hh], ex);
}

// ---- edge pass 3: alpha-weighted, relation-weighted aggregation ----
__global__ void edge_agg_kernel(const int* __restrict__ src, const int* __restrict__ dst,
                                const float* __restrict__ exs, const float* __restrict__ ssum,
                                const float* __restrict__ z, const float* __restrict__ wr,
                                float* __restrict__ vv) {
  int idx = blockIdx.x * 256 + threadIdx.x;
  if (idx >= kE * kH) return;
  int e = idx >> 4, hh = idx & 15;
  int s = src[e], d = dst[e];
  float alpha = exs[idx] / ssum[d * kH + hh];
  const float* zp = z + (size_t)s * kHID + hh * kFH;
  const float* wp = wr + hh * kFH;
  float* vp = vv + (size_t)d * kHID + hh * kFH;
#pragma unroll
  for (int f = 0; f < kFH; f++) atomicAdd(&vp[f], wp[f] * alpha * zp[f]);
}

// ---- relation softmax weights + folded bias ----
__global__ void wsoft_kernel(const float* __restrict__ p, const float* __restrict__ b,
                             float* __restrict__ w, float* __restrict__ c) {
  int f = threadIdx.x;  // 128 threads
  float p0 = p[f], p1 = p[kHID + f], p2 = p[2 * kHID + f];
  float mx = fmaxf(p0, fmaxf(p1, p2));
  float e0 = expf(p0 - mx), e1 = expf(p1 - mx), e2 = expf(p2 - mx);
  float s = e0 + e1 + e2;
  float w0 = e0 / s, w1 = e1 / s, w2 = e2 / s;
  w[f] = w0; w[kHID + f] = w1; w[2 * kHID + f] = w2;
  c[f] = w0 * b[f] + w1 * b[kHID + f] + w2 * b[2 * kHID + f];
}

// ---- v += c[f] broadcast ----
__global__ void addrow_kernel(float* __restrict__ v, const float* __restrict__ c,
                              int total, int m) {
  int idx = blockIdx.x * 256 + threadIdx.x;
  if (idx >= total) return;
  v[idx] += c[idx % m];
}

// ---- final gemv to single output column ----
__global__ void gemv_out_kernel(const float* __restrict__ A, const float* __restrict__ w,
                                const float* __restrict__ b, float* __restrict__ out,
                                int n, int k) {
  int i = blockIdx.x * 256 + threadIdx.x;
  if (i >= n) return;
  const float* a = A + (size_t)i * k;
  float acc = b[0];
#pragma unroll 4
  for (int j = 0; j < k; j++) acc = fmaf(a[j], w[j], acc);
  out[i] = acc;
}

extern "C" void kernel_launch(void* const* d_in, const int* in_sizes, int n_in,
                              void* d_out, int out_size, void* d_ws, size_t ws_size,
                              hipStream_t stream) {
  const float* inputs = (const float*)d_in[0];
  const int*   src    = (const int*)d_in[1];
  const int*   dst    = (const int*)d_in[2];
  const float* e1_W   = (const float*)d_in[3];
  const float* e1_b   = (const float*)d_in[4];
  const float* e_g    = (const float*)d_in[5];
  const float* e_bt   = (const float*)d_in[6];
  const float* e2_W   = (const float*)d_in[7];
  const float* e2_b   = (const float*)d_in[8];
  const float* gat_W  = (const float*)d_in[9];
  const float* gat_al = (const float*)d_in[10];
  const float* gat_ar = (const float*)d_in[11];
  const float* gat_b  = (const float*)d_in[12];
  const float* attn_p = (const float*)d_in[13];
  const float* m1_W   = (const float*)d_in[14];
  const float* m1_b   = (const float*)d_in[15];
  const float* m_g    = (const float*)d_in[16];
  const float* m_bt   = (const float*)d_in[17];
  const float* m2_W   = (const float*)d_in[18];
  const float* m2_b   = (const float*)d_in[19];
  const float* d1_W   = (const float*)d_in[20];
  const float* d1_b   = (const float*)d_in[21];
  const float* d_g    = (const float*)d_in[22];
  const float* d_bt   = (const float*)d_in[23];
  const float* d2_W   = (const float*)d_in[24];
  const float* d2_b   = (const float*)d_in[25];

  float* ws = (float*)d_ws;
  size_t o = 0;
  float* h    = ws + o; o += (size_t)kN * kHID;
  float* bufA = ws + o; o += (size_t)kN * kHID;
  float* bufB = ws + o; o += (size_t)kN * kHID;
  float* vv   = ws + o; o += (size_t)kN * kHID;
  float* exs  = ws + o; o += (size_t)kE * kH;
  float* el   = ws + o; o += (size_t)kN * kH;
  float* er   = ws + o; o += (size_t)kN * kH;
  unsigned* menc = (unsigned*)(ws + o); o += (size_t)kN * kH;
  float* ssum = ws + o; o += (size_t)kN * kH;
  float* mean = ws + o; o += kHID;
  float* var  = ws + o; o += kHID;
  float* wsm  = ws + o; o += kR * kHID;
  float* cvec = ws + o; o += kHID;
  (void)ws_size; (void)in_sizes; (void)n_in; (void)out_size;

  auto nb = [](long t) { return (int)((t + 255) / 256); };
  const long NH = (long)kN * kHID;   // 2.56M
  const long ND = (long)kN * kHD2;   // 1.28M
  const long EH = (long)kE * kH;     // 2.56M
  const long NHh = (long)kN * kH;    // 320K

  // ---- embed MLP (skip=True) ----
  gemm_kernel<<<nb(NH), 256, 0, stream>>>(inputs, e1_W, e1_b, nullptr, bufA, kN, kIN, kHID);
  bn_stats_kernel<<<kHID, 256, 0, stream>>>(bufA, kN, kHID, mean, var);
  bn_relu_kernel<<<nb(NH), 256, 0, stream>>>(bufA, mean, var, e_g, e_bt, bufB, (int)NH, kHID);
  gemm_kernel<<<nb(NH), 256, 0, stream>>>(bufB, e2_W, e2_b, bufB, h, kN, kHID, kHID);

  for (int l = 0; l < kL; l++) {
    wsoft_kernel<<<1, kHID, 0, stream>>>(attn_p + (size_t)l * kR * kHID,
                                         gat_b + (size_t)l * kR * kHID, wsm, cvec);
    hipMemsetAsync(vv, 0, NH * sizeof(float), stream);
    for (int r = 0; r < kR; r++) {
      const float* W = gat_W + ((size_t)(l * kR + r)) * kHID * kHID;
      const float* al = gat_al + (size_t)(l * kR + r) * kH * kFH;
      const float* ar = gat_ar + (size_t)(l * kR + r) * kH * kFH;
      const int* sr = src + (size_t)r * kE;
      const int* dr = dst + (size_t)r * kE;
      gemm_kernel<<<nb(NH), 256, 0, stream>>>(h, W, nullptr, nullptr, bufA, kN, kHID, kHID);
      eler_kernel<<<nb(NHh), 256, 0, stream>>>(bufA, al, ar, el, er);
      hipMemsetAsync(menc, 0, NHh * sizeof(unsigned), stream);
      hipMemsetAsync(ssum, 0, NHh * sizeof(float), stream);
      edge_max_kernel<<<nb(EH), 256, 0, stream>>>(sr, dr, el, er, menc);
      edge_expsum_kernel<<<nb(EH), 256, 0, stream>>>(sr, dr, el, er, menc, exs, ssum);
      edge_agg_kernel<<<nb(EH), 256, 0, stream>>>(sr, dr, exs, ssum, bufA, wsm + (size_t)r * kHID, vv);
    }
    addrow_kernel<<<nb(NH), 256, 0, stream>>>(vv, cvec, (int)NH, kHID);
    // layer MLP (skip=False) + residual h
    gemm_kernel<<<nb(ND), 256, 0, stream>>>(vv, m1_W + (size_t)l * kHID * kHD2,
                                            m1_b + (size_t)l * kHD2, nullptr, bufA, kN, kHID, kHD2);
    bn_stats_kernel<<<kHD2, 256, 0, stream>>>(bufA, kN, kHD2, mean, var);
    bn_relu_kernel<<<nb(ND), 256, 0, stream>>>(bufA, mean, var, m_g + (size_t)l * kHD2,
                                               m_bt + (size_t)l * kHD2, bufB, (int)ND, kHD2);
    gemm_kernel<<<nb(NH), 256, 0, stream>>>(bufB, m2_W + (size_t)l * kHD2 * kHID,
                                            m2_b + (size_t)l * kHID, h, h, kN, kHD2, kHID);
  }

  // ---- decode MLP ----
  gemm_kernel<<<nb(ND), 256, 0, stream>>>(h, d1_W, d1_b, nullptr, bufA, kN, kHID, kHD2);
  bn_stats_kernel<<<kHD2, 256, 0, stream>>>(bufA, kN, kHD2, mean, var);
  bn_relu_kernel<<<nb(ND), 256, 0, stream>>>(bufA, mean, var, d_g, d_bt, bufB, (int)ND, kHD2);
  gemv_out_kernel<<<nb(kN), 256, 0, stream>>>(bufB, d2_W, d2_b, (float*)d_out, kN, kHD2);
}

// Round 2
// 1336.882 us; speedup vs baseline: 3.3761x; 3.3761x over previous
//
#include <hip/hip_runtime.h>
#include <math.h>

// ---- problem constants ----
constexpr int kN   = 20000;
constexpr int kE   = 160000;
constexpr int kR   = 3;
constexpr int kL   = 2;
constexpr int kIN  = 64;
constexpr int kHID = 128;
constexpr int kH   = 16;
constexpr int kFH  = 8;
constexpr int kHD2 = 64;

// ---- generic GEMM: C[n,m] = A[n,k] @ W[k,m] (+bias) (+res) ----
__global__ void gemm_kernel(const float* __restrict__ A, const float* __restrict__ W,
                            const float* __restrict__ bias, const float* __restrict__ res,
                            float* __restrict__ C, int n, int k, int m) {
  int idx = blockIdx.x * 256 + threadIdx.x;
  if (idx >= n * m) return;
  int row = idx / m;
  int col = idx - row * m;
  const float* a = A + (size_t)row * k;
  float acc = bias ? bias[col] : 0.0f;
#pragma unroll 4
  for (int i = 0; i < k; i++) acc = fmaf(a[i], W[(size_t)i * m + col], acc);
  if (res) acc += res[idx];
  C[idx] = acc;
}

// ---- BatchNorm batch statistics: one block per column ----
__global__ void bn_stats_kernel(const float* __restrict__ X, int n, int m,
                                float* __restrict__ mean, float* __restrict__ var) {
  int c = blockIdx.x;
  float s = 0.f, s2 = 0.f;
  for (int i = threadIdx.x; i < n; i += 256) {
    float v = X[(size_t)i * m + c];
    s += v; s2 += v * v;
  }
  __shared__ float sh[256], sh2[256];
  sh[threadIdx.x] = s; sh2[threadIdx.x] = s2;
  __syncthreads();
  for (int off = 128; off > 0; off >>= 1) {
    if (threadIdx.x < off) { sh[threadIdx.x] += sh[threadIdx.x + off]; sh2[threadIdx.x] += sh2[threadIdx.x + off]; }
    __syncthreads();
  }
  if (threadIdx.x == 0) {
    float mu = sh[0] / n;
    mean[c] = mu;
    var[c] = sh2[0] / n - mu * mu;
  }
}

// ---- BN apply + ReLU ----
__global__ void bn_relu_kernel(const float* __restrict__ X, const float* __restrict__ mean,
                               const float* __restrict__ var, const float* __restrict__ g,
                               const float* __restrict__ bt, float* __restrict__ Y,
                               int total, int m) {
  int idx = blockIdx.x * 256 + threadIdx.x;
  if (idx >= total) return;
  int c = idx % m;
  float y = g[c] * (X[idx] - mean[c]) * rsqrtf(var[c] + 1e-5f) + bt[c];
  Y[idx] = fmaxf(y, 0.f);
}

// ---- per-node per-head attention logits: el/er ----
__global__ void eler_kernel(const float* __restrict__ z, const float* __restrict__ al,
                            const float* __restrict__ ar, float* __restrict__ el,
                            float* __restrict__ er) {
  int idx = blockIdx.x * 256 + threadIdx.x;
  if (idx >= kN * kH) return;
  int n = idx >> 4, hh = idx & 15;
  const float* zp = z + (size_t)n * kHID + hh * kFH;
  float sl = 0.f, sr = 0.f;
#pragma unroll
  for (int f = 0; f < kFH; f++) { float zv = zp[f]; sl += zv * al[hh * kFH + f]; sr += zv * ar[hh * kFH + f]; }
  el[idx] = sl; er[idx] = sr;
}

// ---- CSR build: histogram over dst ----
__global__ void hist_kernel(const int* __restrict__ dst, int* __restrict__ deg) {
  int e = blockIdx.x * 256 + threadIdx.x;
  if (e < kE) atomicAdd(&deg[dst[e]], 1);
}

// ---- CSR build: single-block exclusive scan (N=20000) ----
__global__ void scan_kernel(const int* __restrict__ deg, int* __restrict__ rowptr) {
  constexpr int kChunk = (kN + 255) / 256;  // 79
  int t = threadIdx.x;
  int base = t * kChunk;
  int sum = 0;
  for (int i = 0; i < kChunk; i++) { int j = base + i; if (j < kN) sum += deg[j]; }
  __shared__ int partial[256];
  __shared__ int offs[257];
  partial[t] = sum;
  __syncthreads();
  if (t == 0) {
    offs[0] = 0;
    for (int i = 0; i < 256; i++) offs[i + 1] = offs[i] + partial[i];
  }
  __syncthreads();
  int run = offs[t];
  for (int i = 0; i < kChunk; i++) {
    int j = base + i;
    if (j < kN) { rowptr[j] = run; run += deg[j]; }
  }
  if (t == 255) rowptr[kN] = run;  // == kE
}

// ---- CSR build: scatter src ids into dst buckets ----
__global__ void scatter_kernel(const int* __restrict__ src, const int* __restrict__ dst,
                               const int* __restrict__ rowptr, int* __restrict__ cursor,
                               int* __restrict__ col) {
  int e = blockIdx.x * 256 + threadIdx.x;
  if (e < kE) {
    int d = dst[e];
    int p = atomicAdd(&cursor[d], 1);
    col[rowptr[d] + p] = src[e];
  }
}

// ---- fused edge softmax + weighted aggregation: one thread per (dst,head) ----
// online softmax over in-edges; vv[d][h*8+f] (=| +=) wr[h*8+f] * sum(alpha*z[src])
__global__ void gat_fused_kernel(const int* __restrict__ rowptr, const int* __restrict__ col,
                                 const float* __restrict__ z, const float* __restrict__ el,
                                 const float* __restrict__ er, const float* __restrict__ wr,
                                 float* __restrict__ vv, int first) {
  int idx = blockIdx.x * 256 + threadIdx.x;
  if (idx >= kN * kH) return;
  int d = idx >> 4, hh = idx & 15;
  int beg = rowptr[d], end = rowptr[d + 1];
  float erd = er[d * kH + hh];
  float m = -INFINITY, s = 0.f;
  float acc[kFH] = {0.f, 0.f, 0.f, 0.f, 0.f, 0.f, 0.f, 0.f};
  for (int p = beg; p < end; p++) {
    int sv = col[p];
    float v = el[sv * kH + hh] + erd;
    v = v > 0.f ? v : 0.2f * v;
    float ex;
    if (v > m) {
      float scale = expf(m - v);  // exp(-inf)=0 handles first edge
      s *= scale;
#pragma unroll
      for (int f = 0; f < kFH; f++) acc[f] *= scale;
      m = v;
      ex = 1.f;
    } else {
      ex = expf(v - m);
    }
    s += ex;
    const float* zp = z + (size_t)sv * kHID + hh * kFH;
#pragma unroll
    for (int f = 0; f < kFH; f++) acc[f] = fmaf(ex, zp[f], acc[f]);
  }
  float inv = s > 0.f ? 1.f / s : 0.f;
  float* vp = vv + (size_t)d * kHID + hh * kFH;
  const float* wp = wr + hh * kFH;
#pragma unroll
  for (int f = 0; f < kFH; f++) {
    float r = wp[f] * acc[f] * inv;
    vp[f] = first ? r : vp[f] + r;
  }
}

// ---- relation softmax weights + folded bias ----
__global__ void wsoft_kernel(const float* __restrict__ p, const float* __restrict__ b,
                             float* __restrict__ w, float* __restrict__ c) {
  int f = threadIdx.x;  // 128 threads
  float p0 = p[f], p1 = p[kHID + f], p2 = p[2 * kHID + f];
  float mx = fmaxf(p0, fmaxf(p1, p2));
  float e0 = expf(p0 - mx), e1 = expf(p1 - mx), e2 = expf(p2 - mx);
  float s = e0 + e1 + e2;
  float w0 = e0 / s, w1 = e1 / s, w2 = e2 / s;
  w[f] = w0; w[kHID + f] = w1; w[2 * kHID + f] = w2;
  c[f] = w0 * b[f] + w1 * b[kHID + f] + w2 * b[2 * kHID + f];
}

// ---- v += c[f] broadcast ----
__global__ void addrow_kernel(float* __restrict__ v, const float* __restrict__ c,
                              int total, int m) {
  int idx = blockIdx.x * 256 + threadIdx.x;
  if (idx >= total) return;
  v[idx] += c[idx % m];
}

// ---- final gemv to single output column ----
__global__ void gemv_out_kernel(const float* __restrict__ A, const float* __restrict__ w,
                                const float* __restrict__ b, float* __restrict__ out,
                                int n, int k) {
  int i = blockIdx.x * 256 + threadIdx.x;
  if (i >= n) return;
  const float* a = A + (size_t)i * k;
  float acc = b[0];
#pragma unroll 4
  for (int j = 0; j < k; j++) acc = fmaf(a[j], w[j], acc);
  out[i] = acc;
}

extern "C" void kernel_launch(void* const* d_in, const int* in_sizes, int n_in,
                              void* d_out, int out_size, void* d_ws, size_t ws_size,
                              hipStream_t stream) {
  const float* inputs = (const float*)d_in[0];
  const int*   src    = (const int*)d_in[1];
  const int*   dst    = (const int*)d_in[2];
  const float* e1_W   = (const float*)d_in[3];
  const float* e1_b   = (const float*)d_in[4];
  const float* e_g    = (const float*)d_in[5];
  const float* e_bt   = (const float*)d_in[6];
  const float* e2_W   = (const float*)d_in[7];
  const float* e2_b   = (const float*)d_in[8];
  const float* gat_W  = (const float*)d_in[9];
  const float* gat_al = (const float*)d_in[10];
  const float* gat_ar = (const float*)d_in[11];
  const float* gat_b  = (const float*)d_in[12];
  const float* attn_p = (const float*)d_in[13];
  const float* m1_W   = (const float*)d_in[14];
  const float* m1_b   = (const float*)d_in[15];
  const float* m_g    = (const float*)d_in[16];
  const float* m_bt   = (const float*)d_in[17];
  const float* m2_W   = (const float*)d_in[18];
  const float* m2_b   = (const float*)d_in[19];
  const float* d1_W   = (const float*)d_in[20];
  const float* d1_b   = (const float*)d_in[21];
  const float* d_g    = (const float*)d_in[22];
  const float* d_bt   = (const float*)d_in[23];
  const float* d2_W   = (const float*)d_in[24];
  const float* d2_b   = (const float*)d_in[25];

  float* ws = (float*)d_ws;
  size_t o = 0;
  float* h    = ws + o; o += (size_t)kN * kHID;
  float* bufA = ws + o; o += (size_t)kN * kHID;
  float* bufB = ws + o; o += (size_t)kN * kHID;
  float* vv   = ws + o; o += (size_t)kN * kHID;
  float* el   = ws + o; o += (size_t)kN * kH;
  float* er   = ws + o; o += (size_t)kN * kH;
  float* mean = ws + o; o += kHID;
  float* var  = ws + o; o += kHID;
  float* wsm  = ws + o; o += kR * kHID;
  float* cvec = ws + o; o += kHID;
  int* rowptr = (int*)(ws + o); o += (size_t)kR * (kN + 1);
  int* colidx = (int*)(ws + o); o += (size_t)kR * kE;
  int* deg    = (int*)(ws + o); o += kN;
  int* cursor = (int*)(ws + o); o += kN;
  (void)ws_size; (void)in_sizes; (void)n_in; (void)out_size;

  auto nb = [](long t) { return (int)((t + 255) / 256); };
  const long NH = (long)kN * kHID;   // 2.56M
  const long ND = (long)kN * kHD2;   // 1.28M
  const long NHh = (long)kN * kH;    // 320K

  // ---- build per-relation CSR grouped by dst (reused across both layers) ----
  for (int r = 0; r < kR; r++) {
    const int* dr = dst + (size_t)r * kE;
    const int* sr = src + (size_t)r * kE;
    int* rp = rowptr + (size_t)r * (kN + 1);
    int* ci = colidx + (size_t)r * kE;
    hipMemsetAsync(deg, 0, kN * sizeof(int), stream);
    hipMemsetAsync(cursor, 0, kN * sizeof(int), stream);
    hist_kernel<<<nb(kE), 256, 0, stream>>>(dr, deg);
    scan_kernel<<<1, 256, 0, stream>>>(deg, rp);
    scatter_kernel<<<nb(kE), 256, 0, stream>>>(sr, dr, rp, cursor, ci);
  }

  // ---- embed MLP (skip=True) ----
  gemm_kernel<<<nb(NH), 256, 0, stream>>>(inputs, e1_W, e1_b, nullptr, bufA, kN, kIN, kHID);
  bn_stats_kernel<<<kHID, 256, 0, stream>>>(bufA, kN, kHID, mean, var);
  bn_relu_kernel<<<nb(NH), 256, 0, stream>>>(bufA, mean, var, e_g, e_bt, bufB, (int)NH, kHID);
  gemm_kernel<<<nb(NH), 256, 0, stream>>>(bufB, e2_W, e2_b, bufB, h, kN, kHID, kHID);

  for (int l = 0; l < kL; l++) {
    wsoft_kernel<<<1, kHID, 0, stream>>>(attn_p + (size_t)l * kR * kHID,
                                         gat_b + (size_t)l * kR * kHID, wsm, cvec);
    for (int r = 0; r < kR; r++) {
      const float* W = gat_W + ((size_t)(l * kR + r)) * kHID * kHID;
      const float* al = gat_al + (size_t)(l * kR + r) * kH * kFH;
      const float* ar = gat_ar + (size_t)(l * kR + r) * kH * kFH;
      const int* rp = rowptr + (size_t)r * (kN + 1);
      const int* ci = colidx + (size_t)r * kE;
      gemm_kernel<<<nb(NH), 256, 0, stream>>>(h, W, nullptr, nullptr, bufA, kN, kHID, kHID);
      eler_kernel<<<nb(NHh), 256, 0, stream>>>(bufA, al, ar, el, er);
      gat_fused_kernel<<<nb(NHh), 256, 0, stream>>>(rp, ci, bufA, el, er,
                                                    wsm + (size_t)r * kHID, vv, r == 0);
    }
    addrow_kernel<<<nb(NH), 256, 0, stream>>>(vv, cvec, (int)NH, kHID);
    // layer MLP (skip=False) + residual h
    gemm_kernel<<<nb(ND), 256, 0, stream>>>(vv, m1_W + (size_t)l * kHID * kHD2,
                                            m1_b + (size_t)l * kHD2, nullptr, bufA, kN, kHID, kHD2);
    bn_stats_kernel<<<kHD2, 256, 0, stream>>>(bufA, kN, kHD2, mean, var);
    bn_relu_kernel<<<nb(ND), 256, 0, stream>>>(bufA, mean, var, m_g + (size_t)l * kHD2,
                                               m_bt + (size_t)l * kHD2, bufB, (int)ND, kHD2);
    gemm_kernel<<<nb(NH), 256, 0, stream>>>(bufB, m2_W + (size_t)l * kHD2 * kHID,
                                            m2_b + (size_t)l * kHID, h, h, kN, kHD2, kHID);
  }

  // ---- decode MLP ----
  gemm_kernel<<<nb(ND), 256, 0, stream>>>(h, d1_W, d1_b, nullptr, bufA, kN, kHID, kHD2);
  bn_stats_kernel<<<kHD2, 256, 0, stream>>>(bufA, kN, kHD2, mean, var);
  bn_relu_kernel<<<nb(ND), 256, 0, stream>>>(bufA, mean, var, d_g, d_bt, bufB, (int)ND, kHD2);
  gemv_out_kernel<<<nb(kN), 256, 0, stream>>>(bufB, d2_W, d2_b, (float*)d_out, kN, kHD2);
}

// Round 3
// 804.501 us; speedup vs baseline: 5.6103x; 1.6618x over previous
//
#include <hip/hip_runtime.h>
#include <math.h>

// ---- problem constants ----
constexpr int kN   = 20000;
constexpr int kE   = 160000;
constexpr int kR   = 3;
constexpr int kL   = 2;
constexpr int kIN  = 64;
constexpr int kHID = 128;
constexpr int kH   = 16;
constexpr int kFH  = 8;
constexpr int kHD2 = 64;

// ---- tiled GEMM: C[n,m] = A[n,k] @ W[k,m] (+bias) (+res) ----
// BM=128, BN=64, BK=32, 256 threads, each thread 8 rows x 4 cols.
__global__ __launch_bounds__(256) void tgemm_kernel(
    const float* __restrict__ A, const float* __restrict__ W,
    const float* __restrict__ bias, const float* __restrict__ res,
    float* __restrict__ C, int n, int k, int m) {
  constexpr int BM = 128, BN = 64, BK = 32, TM = 8, TN = 4;
  __shared__ float At[BM][BK + 1];
  __shared__ float Wt[BK][BN];
  const int t  = threadIdx.x;
  const int tx = t & 15;   // col group: cols tx + 16*j
  const int ty = t >> 4;   // row group: rows ty*8 + i
  const int r0 = blockIdx.x * BM;
  const int c0 = blockIdx.y * BN;
  float acc[TM][TN] = {};
  for (int k0 = 0; k0 < k; k0 += BK) {
    // A tile: BM x BK (16 floats / thread, 4x float4 global, scalar LDS stores due to pad)
#pragma unroll
    for (int i = 0; i < 4; i++) {
      int li = t * 16 + i * 4;
      int row = li >> 5, col = li & 31;
      int gr = r0 + row;
      float4 v = make_float4(0.f, 0.f, 0.f, 0.f);
      if (gr < n) v = *(const float4*)&A[(size_t)gr * k + k0 + col];
      At[row][col] = v.x; At[row][col + 1] = v.y;
      At[row][col + 2] = v.z; At[row][col + 3] = v.w;
    }
    // W tile: BK x BN (8 floats / thread)
#pragma unroll
    for (int i = 0; i < 2; i++) {
      int li = t * 8 + i * 4;
      int row = li >> 6, col = li & 63;
      *(float4*)&Wt[row][col] = *(const float4*)&W[(size_t)(k0 + row) * m + c0 + col];
    }
    __syncthreads();
#pragma unroll
    for (int kk = 0; kk < BK; kk++) {
      float a[TM], w[TN];
#pragma unroll
      for (int i = 0; i < TM; i++) a[i] = At[ty * TM + i][kk];
#pragma unroll
      for (int j = 0; j < TN; j++) w[j] = Wt[kk][tx + 16 * j];
#pragma unroll
      for (int i = 0; i < TM; i++)
#pragma unroll
        for (int j = 0; j < TN; j++) acc[i][j] = fmaf(a[i], w[j], acc[i][j]);
    }
    __syncthreads();
  }
#pragma unroll
  for (int i = 0; i < TM; i++) {
    int gr = r0 + ty * TM + i;
    if (gr < n) {
#pragma unroll
      for (int j = 0; j < TN; j++) {
        int gc = c0 + tx + 16 * j;
        float v = acc[i][j];
        if (bias) v += bias[gc];
        if (res)  v += res[(size_t)gr * m + gc];
        C[(size_t)gr * m + gc] = v;
      }
    }
  }
}

// ---- BN stats, phase 1: coalesced partial sums + atomics ----
// block covers 128 rows; thread t owns col t%m, rows stride 256/m.
__global__ void bn_part_kernel(const float* __restrict__ X, int n, int m,
                               float* __restrict__ sacc, float* __restrict__ s2acc) {
  int t = threadIdx.x;
  int c = t % m;
  int rr = t / m;
  int stride = 256 / m;
  int r0 = blockIdx.x * 128;
  float s = 0.f, s2 = 0.f;
  for (int r = rr; r < 128; r += stride) {
    int gr = r0 + r;
    if (gr < n) { float v = X[(size_t)gr * m + c]; s += v; s2 += v * v; }
  }
  __shared__ float sh[256], sh2[256];
  sh[t] = s; sh2[t] = s2;
  __syncthreads();
  if (t < m) {
    for (int i = 1; i < stride; i++) { s += sh[t + i * m]; s2 += sh2[t + i * m]; }
    atomicAdd(&sacc[c], s);
    atomicAdd(&s2acc[c], s2);
  }
}

// ---- BN apply + ReLU (reads raw sums) ----
__global__ void bn_relu_kernel(const float* __restrict__ X, const float* __restrict__ sacc,
                               const float* __restrict__ s2acc, const float* __restrict__ g,
                               const float* __restrict__ bt, float* __restrict__ Y,
                               int total, int m, float invn) {
  int idx = blockIdx.x * 256 + threadIdx.x;
  if (idx >= total) return;
  int c = idx % m;
  float mu = sacc[c] * invn;
  float var = s2acc[c] * invn - mu * mu;
  float y = g[c] * (X[idx] - mu) * rsqrtf(var + 1e-5f) + bt[c];
  Y[idx] = fmaxf(y, 0.f);
}

// ---- per-node per-head attention logits: el/er ----
__global__ void eler_kernel(const float* __restrict__ z, const float* __restrict__ al,
                            const float* __restrict__ ar, float* __restrict__ el,
                            float* __restrict__ er) {
  int idx = blockIdx.x * 256 + threadIdx.x;
  if (idx >= kN * kH) return;
  int n = idx >> 4, hh = idx & 15;
  const float* zp = z + (size_t)n * kHID + hh * kFH;
  float sl = 0.f, sr = 0.f;
#pragma unroll
  for (int f = 0; f < kFH; f++) { float zv = zp[f]; sl += zv * al[hh * kFH + f]; sr += zv * ar[hh * kFH + f]; }
  el[idx] = sl; er[idx] = sr;
}

// ---- CSR build ----
__global__ void hist_kernel(const int* __restrict__ dst, int* __restrict__ deg) {
  int e = blockIdx.x * 256 + threadIdx.x;
  if (e < kE) atomicAdd(&deg[dst[e]], 1);
}

__global__ void scan_kernel(const int* __restrict__ deg, int* __restrict__ rowptr) {
  constexpr int kChunk = (kN + 255) / 256;  // 79
  int t = threadIdx.x;
  int base = t * kChunk;
  int sum = 0;
  for (int i = 0; i < kChunk; i++) { int j = base + i; if (j < kN) sum += deg[j]; }
  __shared__ int partial[256];
  __shared__ int offs[257];
  partial[t] = sum;
  __syncthreads();
  if (t == 0) {
    offs[0] = 0;
    for (int i = 0; i < 256; i++) offs[i + 1] = offs[i] + partial[i];
  }
  __syncthreads();
  int run = offs[t];
  for (int i = 0; i < kChunk; i++) {
    int j = base + i;
    if (j < kN) { rowptr[j] = run; run += deg[j]; }
  }
  if (t == 255) rowptr[kN] = run;
}

__global__ void scatter_kernel(const int* __restrict__ src, const int* __restrict__ dst,
                               const int* __restrict__ rowptr, int* __restrict__ cursor,
                               int* __restrict__ col) {
  int e = blockIdx.x * 256 + threadIdx.x;
  if (e < kE) {
    int d = dst[e];
    int p = atomicAdd(&cursor[d], 1);
    col[rowptr[d] + p] = src[e];
  }
}

// ---- fused edge softmax + weighted aggregation: one thread per (dst,head) ----
__global__ void gat_fused_kernel(const int* __restrict__ rowptr, const int* __restrict__ col,
                                 const float* __restrict__ z, const float* __restrict__ el,
                                 const float* __restrict__ er, const float* __restrict__ wr,
                                 const float* __restrict__ cvec,
                                 float* __restrict__ vv, int first) {
  int idx = blockIdx.x * 256 + threadIdx.x;
  if (idx >= kN * kH) return;
  int d = idx >> 4, hh = idx & 15;
  int beg = rowptr[d], end = rowptr[d + 1];
  float erd = er[d * kH + hh];
  float m = -INFINITY, s = 0.f;
  float acc[kFH] = {0.f, 0.f, 0.f, 0.f, 0.f, 0.f, 0.f, 0.f};
  for (int p = beg; p < end; p++) {
    int sv = col[p];
    float v = el[sv * kH + hh] + erd;
    v = v > 0.f ? v : 0.2f * v;
    float ex;
    if (v > m) {
      float scale = expf(m - v);
      s *= scale;
#pragma unroll
      for (int f = 0; f < kFH; f++) acc[f] *= scale;
      m = v;
      ex = 1.f;
    } else {
      ex = expf(v - m);
    }
    s += ex;
    const float* zp = z + (size_t)sv * kHID + hh * kFH;
#pragma unroll
    for (int f = 0; f < kFH; f++) acc[f] = fmaf(ex, zp[f], acc[f]);
  }
  float inv = s > 0.f ? 1.f / s : 0.f;
  float* vp = vv + (size_t)d * kHID + hh * kFH;
  const float* wp = wr + hh * kFH;
#pragma unroll
  for (int f = 0; f < kFH; f++) {
    float r = wp[f] * acc[f] * inv;
    vp[f] = first ? (r + cvec[hh * kFH + f]) : (vp[f] + r);
  }
}

// ---- relation softmax weights + folded bias ----
__global__ void wsoft_kernel(const float* __restrict__ p, const float* __restrict__ b,
                             float* __restrict__ w, float* __restrict__ c) {
  int f = threadIdx.x;  // 128 threads
  float p0 = p[f], p1 = p[kHID + f], p2 = p[2 * kHID + f];
  float mx = fmaxf(p0, fmaxf(p1, p2));
  float e0 = expf(p0 - mx), e1 = expf(p1 - mx), e2 = expf(p2 - mx);
  float s = e0 + e1 + e2;
  float w0 = e0 / s, w1 = e1 / s, w2 = e2 / s;
  w[f] = w0; w[kHID + f] = w1; w[2 * kHID + f] = w2;
  c[f] = w0 * b[f] + w1 * b[kHID + f] + w2 * b[2 * kHID + f];
}

// ---- final gemv to single output column ----
__global__ void gemv_out_kernel(const float* __restrict__ A, const float* __restrict__ w,
                                const float* __restrict__ b, float* __restrict__ out,
                                int n, int k) {
  int i = blockIdx.x * 256 + threadIdx.x;
  if (i >= n) return;
  const float* a = A + (size_t)i * k;
  float acc = b[0];
#pragma unroll 4
  for (int j = 0; j < k; j++) acc = fmaf(a[j], w[j], acc);
  out[i] = acc;
}

extern "C" void kernel_launch(void* const* d_in, const int* in_sizes, int n_in,
                              void* d_out, int out_size, void* d_ws, size_t ws_size,
                              hipStream_t stream) {
  const float* inputs = (const float*)d_in[0];
  const int*   src    = (const int*)d_in[1];
  const int*   dst    = (const int*)d_in[2];
  const float* e1_W   = (const float*)d_in[3];
  const float* e1_b   = (const float*)d_in[4];
  const float* e_g    = (const float*)d_in[5];
  const float* e_bt   = (const float*)d_in[6];
  const float* e2_W   = (const float*)d_in[7];
  const float* e2_b   = (const float*)d_in[8];
  const float* gat_W  = (const float*)d_in[9];
  const float* gat_al = (const float*)d_in[10];
  const float* gat_ar = (const float*)d_in[11];
  const float* gat_b  = (const float*)d_in[12];
  const float* attn_p = (const float*)d_in[13];
  const float* m1_W   = (const float*)d_in[14];
  const float* m1_b   = (const float*)d_in[15];
  const float* m_g    = (const float*)d_in[16];
  const float* m_bt   = (const float*)d_in[17];
  const float* m2_W   = (const float*)d_in[18];
  const float* m2_b   = (const float*)d_in[19];
  const float* d1_W   = (const float*)d_in[20];
  const float* d1_b   = (const float*)d_in[21];
  const float* d_g    = (const float*)d_in[22];
  const float* d_bt   = (const float*)d_in[23];
  const float* d2_W   = (const float*)d_in[24];
  const float* d2_b   = (const float*)d_in[25];

  float* ws = (float*)d_ws;
  size_t o = 0;
  float* h    = ws + o; o += (size_t)kN * kHID;
  float* bufA = ws + o; o += (size_t)kN * kHID;
  float* bufB = ws + o; o += (size_t)kN * kHID;
  float* vv   = ws + o; o += (size_t)kN * kHID;
  float* el   = ws + o; o += (size_t)kN * kH;
  float* er   = ws + o; o += (size_t)kN * kH;
  float* bnacc = ws + o; o += 2 * kHID;   // sacc | s2acc
  float* wsm  = ws + o; o += kR * kHID;
  float* cvec = ws + o; o += kHID;
  int* rowptr = (int*)(ws + o); o += (size_t)kR * (kN + 1);
  int* colidx = (int*)(ws + o); o += (size_t)kR * kE;
  int* deg    = (int*)(ws + o); o += kN;
  int* cursor = (int*)(ws + o); o += kN;
  (void)ws_size; (void)in_sizes; (void)n_in; (void)out_size;

  auto nb = [](long t) { return (int)((t + 255) / 256); };
  const long NH = (long)kN * kHID;
  const long ND = (long)kN * kHD2;
  const long NHh = (long)kN * kH;
  const int  RB = (kN + 127) / 128;       // bn_part blocks (157)
  const dim3 gemm_g128((kN + 127) / 128, 2);   // m=128
  const dim3 gemm_g64((kN + 127) / 128, 1);    // m=64
  const float invn = 1.0f / kN;

  // ---- build per-relation CSR grouped by dst ----
  for (int r = 0; r < kR; r++) {
    const int* dr = dst + (size_t)r * kE;
    const int* sr = src + (size_t)r * kE;
    int* rp = rowptr + (size_t)r * (kN + 1);
    int* ci = colidx + (size_t)r * kE;
    hipMemsetAsync(deg, 0, kN * sizeof(int), stream);
    hipMemsetAsync(cursor, 0, kN * sizeof(int), stream);
    hist_kernel<<<nb(kE), 256, 0, stream>>>(dr, deg);
    scan_kernel<<<1, 256, 0, stream>>>(deg, rp);
    scatter_kernel<<<nb(kE), 256, 0, stream>>>(sr, dr, rp, cursor, ci);
  }

  // ---- embed MLP (skip=True) ----
  tgemm_kernel<<<gemm_g128, 256, 0, stream>>>(inputs, e1_W, e1_b, nullptr, bufA, kN, kIN, kHID);
  hipMemsetAsync(bnacc, 0, 2 * kHID * sizeof(float), stream);
  bn_part_kernel<<<RB, 256, 0, stream>>>(bufA, kN, kHID, bnacc, bnacc + kHID);
  bn_relu_kernel<<<nb(NH), 256, 0, stream>>>(bufA, bnacc, bnacc + kHID, e_g, e_bt, bufB, (int)NH, kHID, invn);
  tgemm_kernel<<<gemm_g128, 256, 0, stream>>>(bufB, e2_W, e2_b, bufB, h, kN, kHID, kHID);

  for (int l = 0; l < kL; l++) {
    wsoft_kernel<<<1, kHID, 0, stream>>>(attn_p + (size_t)l * kR * kHID,
                                         gat_b + (size_t)l * kR * kHID, wsm, cvec);
    for (int r = 0; r < kR; r++) {
      const float* W = gat_W + ((size_t)(l * kR + r)) * kHID * kHID;
      const float* al = gat_al + (size_t)(l * kR + r) * kH * kFH;
      const float* ar = gat_ar + (size_t)(l * kR + r) * kH * kFH;
      const int* rp = rowptr + (size_t)r * (kN + 1);
      const int* ci = colidx + (size_t)r * kE;
      tgemm_kernel<<<gemm_g128, 256, 0, stream>>>(h, W, nullptr, nullptr, bufA, kN, kHID, kHID);
      eler_kernel<<<nb(NHh), 256, 0, stream>>>(bufA, al, ar, el, er);
      gat_fused_kernel<<<nb(NHh), 256, 0, stream>>>(rp, ci, bufA, el, er,
                                                    wsm + (size_t)r * kHID, cvec, vv, r == 0);
    }
    // layer MLP (skip=False) + residual h
    tgemm_kernel<<<gemm_g64, 256, 0, stream>>>(vv, m1_W + (size_t)l * kHID * kHD2,
                                               m1_b + (size_t)l * kHD2, nullptr, bufA, kN, kHID, kHD2);
    hipMemsetAsync(bnacc, 0, 2 * kHD2 * sizeof(float), stream);
    bn_part_kernel<<<RB, 256, 0, stream>>>(bufA, kN, kHD2, bnacc, bnacc + kHD2);
    bn_relu_kernel<<<nb(ND), 256, 0, stream>>>(bufA, bnacc, bnacc + kHD2, m_g + (size_t)l * kHD2,
                                               m_bt + (size_t)l * kHD2, bufB, (int)ND, kHD2, invn);
    tgemm_kernel<<<gemm_g128, 256, 0, stream>>>(bufB, m2_W + (size_t)l * kHD2 * kHID,
                                                m2_b + (size_t)l * kHID, h, h, kN, kHD2, kHID);
  }

  // ---- decode MLP ----
  tgemm_kernel<<<gemm_g64, 256, 0, stream>>>(h, d1_W, d1_b, nullptr, bufA, kN, kHID, kHD2);
  hipMemsetAsync(bnacc, 0, 2 * kHD2 * sizeof(float), stream);
  bn_part_kernel<<<RB, 256, 0, stream>>>(bufA, kN, kHD2, bnacc, bnacc + kHD2);
  bn_relu_kernel<<<nb(ND), 256, 0, stream>>>(bufA, bnacc, bnacc + kHD2, d_g, d_bt, bufB, (int)ND, kHD2, invn);
  gemv_out_kernel<<<nb(kN), 256, 0, stream>>>(bufB, d2_W, d2_b, (float*)d_out, kN, kHD2);
}

// Round 4
// 486.816 us; speedup vs baseline: 9.2715x; 1.6526x over previous
//
#include <hip/hip_runtime.h>
#include <math.h>

// ---- problem constants ----
constexpr int kN   = 20000;
constexpr int kE   = 160000;
constexpr int kR   = 3;
constexpr int kL   = 2;
constexpr int kIN  = 64;
constexpr int kHID = 128;
constexpr int kH   = 16;
constexpr int kFH  = 8;
constexpr int kHD2 = 64;
constexpr int kSB  = (kN + 255) / 256;   // scan blocks per relation = 79

// ---- tiled GEMM with fused epilogues ----
// BM=128, BN=64, BK=32, 256 threads, thread = 8 rows x 4 contiguous cols.
// Optional: bnsc/bnsh  -> apply y=max(x*sc+sh,0) to A elements on load (BN+ReLU fused)
//           bias, res  -> epilogue adds
//           statS      -> atomic col sums/sumsqs (statS[m+c] = sumsq) for BatchNorm
//           al/ar      -> write GAT attention logits el/er (per node, per head)
__global__ __launch_bounds__(256) void tgemm_kernel(
    const float* __restrict__ A, const float* __restrict__ W,
    const float* __restrict__ bias, const float* __restrict__ res,
    const float* __restrict__ bnsc, const float* __restrict__ bnsh,
    float* __restrict__ statS,
    const float* __restrict__ al, const float* __restrict__ ar,
    float* __restrict__ el, float* __restrict__ er,
    float* __restrict__ C, int n, int k, int m) {
  constexpr int BM = 128, BN = 64, BK = 32, TM = 8, TN = 4;
  __shared__ float At[BK][BM];   // column-major A tile: At[kk][row]
  __shared__ float Wt[BK][BN];
  const int t  = threadIdx.x;
  const int tx = t & 15;         // cols tx*4 .. tx*4+3
  const int ty = t >> 4;         // rows ty*8 .. ty*8+7
  const int r0 = blockIdx.x * BM;
  const int c0 = blockIdx.y * BN;
  float acc[TM][TN] = {};
  for (int k0 = 0; k0 < k; k0 += BK) {
#pragma unroll
    for (int i = 0; i < 4; i++) {
      int li = t * 16 + i * 4;
      int row = li >> 5, col = li & 31;
      int gr = r0 + row;
      float4 v = make_float4(0.f, 0.f, 0.f, 0.f);
      if (gr < n) v = *(const float4*)&A[(size_t)gr * k + k0 + col];
      if (bnsc) {
        int c = k0 + col;
        v.x = fmaxf(fmaf(v.x, bnsc[c],     bnsh[c]),     0.f);
        v.y = fmaxf(fmaf(v.y, bnsc[c + 1], bnsh[c + 1]), 0.f);
        v.z = fmaxf(fmaf(v.z, bnsc[c + 2], bnsh[c + 2]), 0.f);
        v.w = fmaxf(fmaf(v.w, bnsc[c + 3], bnsh[c + 3]), 0.f);
      }
      At[col][row] = v.x; At[col + 1][row] = v.y;
      At[col + 2][row] = v.z; At[col + 3][row] = v.w;
    }
#pragma unroll
    for (int i = 0; i < 2; i++) {
      int li = t * 8 + i * 4;
      int row = li >> 6, col = li & 63;
      *(float4*)&Wt[row][col] = *(const float4*)&W[(size_t)(k0 + row) * m + c0 + col];
    }
    __syncthreads();
#pragma unroll
    for (int kk = 0; kk < BK; kk++) {
      float4 a0 = *(const float4*)&At[kk][ty * TM];
      float4 a1 = *(const float4*)&At[kk][ty * TM + 4];
      float4 w0 = *(const float4*)&Wt[kk][tx * TN];
      float a[TM] = {a0.x, a0.y, a0.z, a0.w, a1.x, a1.y, a1.z, a1.w};
      float w[TN] = {w0.x, w0.y, w0.z, w0.w};
#pragma unroll
      for (int i = 0; i < TM; i++)
#pragma unroll
        for (int j = 0; j < TN; j++) acc[i][j] = fmaf(a[i], w[j], acc[i][j]);
    }
    __syncthreads();
  }
  // epilogue: bias/res, float4 store; acc becomes final stored values
#pragma unroll
  for (int i = 0; i < TM; i++) {
    int gr = r0 + ty * TM + i;
    if (gr < n) {
      int gc = c0 + tx * TN;
      float4 v = make_float4(acc[i][0], acc[i][1], acc[i][2], acc[i][3]);
      if (bias) { v.x += bias[gc]; v.y += bias[gc + 1]; v.z += bias[gc + 2]; v.w += bias[gc + 3]; }
      if (res) {
        float4 rr = *(const float4*)&res[(size_t)gr * m + gc];
        v.x += rr.x; v.y += rr.y; v.z += rr.z; v.w += rr.w;
      }
      *(float4*)&C[(size_t)gr * m + gc] = v;
      acc[i][0] = v.x; acc[i][1] = v.y; acc[i][2] = v.z; acc[i][3] = v.w;
    }
  }
  if (statS) {  // fused BatchNorm column statistics
    float s[TN] = {}, s2[TN] = {};
#pragma unroll
    for (int i = 0; i < TM; i++) {
      int gr = r0 + ty * TM + i;
      if (gr < n) {
#pragma unroll
        for (int j = 0; j < TN; j++) { float v = acc[i][j]; s[j] += v; s2[j] += v * v; }
      }
    }
    float* redS  = (float*)At;        // reuse LDS (all threads past final barrier)
    float* redS2 = redS + 1024;
#pragma unroll
    for (int j = 0; j < TN; j++) {
      redS[ty * 64 + tx * TN + j]  = s[j];
      redS2[ty * 64 + tx * TN + j] = s2[j];
    }
    __syncthreads();
    if (ty == 0) {
#pragma unroll
      for (int j = 0; j < TN; j++) {
        float ts = 0.f, ts2 = 0.f;
        for (int q = 0; q < 16; q++) { ts += redS[q * 64 + tx * TN + j]; ts2 += redS2[q * 64 + tx * TN + j]; }
        atomicAdd(&statS[c0 + tx * TN + j], ts);
        atomicAdd(&statS[m + c0 + tx * TN + j], ts2);
      }
    }
  }
  if (al) {  // fused GAT logits: this thread's 4 cols are one half of one head
    int hd  = (c0 >> 3) + (tx >> 1);     // global head 0..15
    int ofs = (tx & 1) * 4;              // half within head
    float alv[TN], arv[TN];
#pragma unroll
    for (int j = 0; j < TN; j++) { alv[j] = al[hd * kFH + ofs + j]; arv[j] = ar[hd * kFH + ofs + j]; }
#pragma unroll
    for (int i = 0; i < TM; i++) {
      int gr = r0 + ty * TM + i;
      float pl = acc[i][0] * alv[0] + acc[i][1] * alv[1] + acc[i][2] * alv[2] + acc[i][3] * alv[3];
      float pr = acc[i][0] * arv[0] + acc[i][1] * arv[1] + acc[i][2] * arv[2] + acc[i][3] * arv[3];
      pl += __shfl_xor(pl, 1, 64);       // partner lane = other half of head
      pr += __shfl_xor(pr, 1, 64);
      if (!(tx & 1) && gr < n) { el[gr * kH + hd] = pl; er[gr * kH + hd] = pr; }
    }
  }
}

// ---- fold BN stats into scale/shift: y = x*sc + sh ----
__global__ void bnfold_kernel(const float* __restrict__ statS, const float* __restrict__ g,
                              const float* __restrict__ bt, float* __restrict__ sc,
                              float* __restrict__ sh, int dim, float invn) {
  int c = threadIdx.x;
  if (c >= dim) return;
  float mu  = statS[c] * invn;
  float var = statS[dim + c] * invn - mu * mu;
  float s = g[c] * rsqrtf(var + 1e-5f);
  sc[c] = s; sh[c] = bt[c] - mu * s;
}

// ---- BN apply + ReLU (embed only; float4) ----
__global__ void bn_relu_kernel(const float* __restrict__ X, const float* __restrict__ sc,
                               const float* __restrict__ sh, float* __restrict__ Y,
                               int total4, int m) {
  int i4 = blockIdx.x * 256 + threadIdx.x;
  if (i4 >= total4) return;
  int c = (i4 * 4) % m;
  float4 x = ((const float4*)X)[i4];
  float4 y;
  y.x = fmaxf(fmaf(x.x, sc[c],     sh[c]),     0.f);
  y.y = fmaxf(fmaf(x.y, sc[c + 1], sh[c + 1]), 0.f);
  y.z = fmaxf(fmaf(x.z, sc[c + 2], sh[c + 2]), 0.f);
  y.w = fmaxf(fmaf(x.w, sc[c + 3], sh[c + 3]), 0.f);
  ((float4*)Y)[i4] = y;
}

// ---- CSR build (batched over relations via blockIdx.y) ----
__global__ void hist_kernel(const int* __restrict__ dst, int* __restrict__ deg) {
  int r = blockIdx.y;
  int e = blockIdx.x * 256 + threadIdx.x;
  if (e < kE) atomicAdd(&deg[r * kN + dst[r * kE + e]], 1);
}

__global__ void bsum_kernel(const int* __restrict__ deg, int* __restrict__ bsum) {
  int r = blockIdx.y;
  int j = blockIdx.x * 256 + threadIdx.x;
  int x = (j < kN) ? deg[r * kN + j] : 0;
  __shared__ int shm[256];
  shm[threadIdx.x] = x;
  __syncthreads();
  for (int off = 128; off > 0; off >>= 1) {
    if (threadIdx.x < off) shm[threadIdx.x] += shm[threadIdx.x + off];
    __syncthreads();
  }
  if (threadIdx.x == 0) bsum[r * kSB + blockIdx.x] = shm[0];
}

__global__ void bscan_kernel(int* __restrict__ bsum) {
  __shared__ int shm[kR * kSB];
  int t = threadIdx.x;
  for (int i = t; i < kR * kSB; i += 256) shm[i] = bsum[i];
  __syncthreads();
  if (t < kR) {
    int run = 0;
    for (int b = 0; b < kSB; b++) { int v = shm[t * kSB + b]; shm[t * kSB + b] = run; run += v; }
  }
  __syncthreads();
  for (int i = t; i < kR * kSB; i += 256) bsum[i] = shm[i];
}

__global__ void scan2_kernel(const int* __restrict__ deg, const int* __restrict__ bsum,
                             int* __restrict__ rowptr) {
  int r = blockIdx.y;
  int t = threadIdx.x;
  int j = blockIdx.x * 256 + t;
  int x = (j < kN) ? deg[r * kN + j] : 0;
  int lane = t & 63, w = t >> 6;
  int v = x;
  for (int off = 1; off < 64; off <<= 1) {
    int y = __shfl_up(v, off, 64);
    if (lane >= off) v += y;
  }
  __shared__ int wtot[4];
  if (lane == 63) wtot[w] = v;
  __syncthreads();
  int add = bsum[r * kSB + blockIdx.x];
  for (int i = 0; i < 4; i++) if (i < w) add += wtot[i];
  if (j < kN) rowptr[r * (kN + 1) + j] = add + v - x;
  if (blockIdx.x == 0 && t == 0) rowptr[r * (kN + 1) + kN] = kE;
}

__global__ void scatter_kernel(const int* __restrict__ src, const int* __restrict__ dst,
                               const int* __restrict__ rowptr, int* __restrict__ cursor,
                               int* __restrict__ col) {
  int r = blockIdx.y;
  int e = blockIdx.x * 256 + threadIdx.x;
  if (e < kE) {
    int d = dst[r * kE + e];
    int p = atomicAdd(&cursor[r * kN + d], 1);
    col[r * kE + rowptr[r * (kN + 1) + d] + p] = src[r * kE + e];
  }
}

// ---- fused edge softmax + weighted aggregation: thread per (dst,head) ----
// no max-subtraction: logits are O(0.1) here, exp cannot overflow; result identical.
__global__ void gat_fused_kernel(const int* __restrict__ rowptr, const int* __restrict__ col,
                                 const float* __restrict__ z, const float* __restrict__ el,
                                 const float* __restrict__ er, const float* __restrict__ wr,
                                 const float* __restrict__ cvec,
                                 float* __restrict__ vv, int first) {
  int idx = blockIdx.x * 256 + threadIdx.x;
  if (idx >= kN * kH) return;
  int d = idx >> 4, hh = idx & 15;
  int beg = rowptr[d], end = rowptr[d + 1];
  float erd = er[(d << 4) + hh];
  float s = 0.f;
  float4 a0 = make_float4(0.f, 0.f, 0.f, 0.f), a1 = a0;
  for (int p = beg; p < end; p++) {
    int sv = col[p];
    float v = el[(sv << 4) + hh] + erd;
    v = v > 0.f ? v : 0.2f * v;
    float ex = __expf(v);
    s += ex;
    const float4* zp = (const float4*)(z + ((size_t)sv << 7) + (hh << 3));
    float4 z0 = zp[0], z1 = zp[1];
    a0.x = fmaf(ex, z0.x, a0.x); a0.y = fmaf(ex, z0.y, a0.y);
    a0.z = fmaf(ex, z0.z, a0.z); a0.w = fmaf(ex, z0.w, a0.w);
    a1.x = fmaf(ex, z1.x, a1.x); a1.y = fmaf(ex, z1.y, a1.y);
    a1.z = fmaf(ex, z1.z, a1.z); a1.w = fmaf(ex, z1.w, a1.w);
  }
  float inv = s > 0.f ? 1.f / s : 0.f;
  const float* wp = wr + (hh << 3);
  float4 w0 = *(const float4*)wp, w1 = *(const float4*)(wp + 4);
  float4 r0, r1;
  r0.x = w0.x * a0.x * inv; r0.y = w0.y * a0.y * inv;
  r0.z = w0.z * a0.z * inv; r0.w = w0.w * a0.w * inv;
  r1.x = w1.x * a1.x * inv; r1.y = w1.y * a1.y * inv;
  r1.z = w1.z * a1.z * inv; r1.w = w1.w * a1.w * inv;
  float4* vp = (float4*)(vv + ((size_t)d << 7) + (hh << 3));
  if (first) {
    const float4* cv = (const float4*)(cvec + (hh << 3));
    float4 c0 = cv[0], c1 = cv[1];
    r0.x += c0.x; r0.y += c0.y; r0.z += c0.z; r0.w += c0.w;
    r1.x += c1.x; r1.y += c1.y; r1.z += c1.z; r1.w += c1.w;
  } else {
    float4 p0 = vp[0], p1 = vp[1];
    r0.x += p0.x; r0.y += p0.y; r0.z += p0.z; r0.w += p0.w;
    r1.x += p1.x; r1.y += p1.y; r1.z += p1.z; r1.w += p1.w;
  }
  vp[0] = r0; vp[1] = r1;
}

// ---- relation softmax weights + folded bias ----
__global__ void wsoft_kernel(const float* __restrict__ p, const float* __restrict__ b,
                             float* __restrict__ w, float* __restrict__ c) {
  int f = threadIdx.x;  // 128 threads
  float p0 = p[f], p1 = p[kHID + f], p2 = p[2 * kHID + f];
  float mx = fmaxf(p0, fmaxf(p1, p2));
  float e0 = __expf(p0 - mx), e1 = __expf(p1 - mx), e2 = __expf(p2 - mx);
  float s = e0 + e1 + e2;
  float w0 = e0 / s, w1 = e1 / s, w2 = e2 / s;
  w[f] = w0; w[kHID + f] = w1; w[2 * kHID + f] = w2;
  c[f] = w0 * b[f] + w1 * b[kHID + f] + w2 * b[2 * kHID + f];
}

// ---- final gemv with fused BN+ReLU on input ----
__global__ void gemv_out_kernel(const float* __restrict__ A, const float* __restrict__ sc,
                                const float* __restrict__ sh, const float* __restrict__ w,
                                const float* __restrict__ b, float* __restrict__ out,
                                int n, int k) {
  int i = blockIdx.x * 256 + threadIdx.x;
  if (i >= n) return;
  const float4* a = (const float4*)(A + (size_t)i * k);
  float acc = b[0];
  for (int j4 = 0; j4 < k / 4; j4++) {
    float4 x = a[j4];
    int c = j4 * 4;
    acc = fmaf(fmaxf(fmaf(x.x, sc[c],     sh[c]),     0.f), w[c],     acc);
    acc = fmaf(fmaxf(fmaf(x.y, sc[c + 1], sh[c + 1]), 0.f), w[c + 1], acc);
    acc = fmaf(fmaxf(fmaf(x.z, sc[c + 2], sh[c + 2]), 0.f), w[c + 2], acc);
    acc = fmaf(fmaxf(fmaf(x.w, sc[c + 3], sh[c + 3]), 0.f), w[c + 3], acc);
  }
  out[i] = acc;
}

extern "C" void kernel_launch(void* const* d_in, const int* in_sizes, int n_in,
                              void* d_out, int out_size, void* d_ws, size_t ws_size,
                              hipStream_t stream) {
  const float* inputs = (const float*)d_in[0];
  const int*   src    = (const int*)d_in[1];
  const int*   dst    = (const int*)d_in[2];
  const float* e1_W   = (const float*)d_in[3];
  const float* e1_b   = (const float*)d_in[4];
  const float* e_g    = (const float*)d_in[5];
  const float* e_bt   = (const float*)d_in[6];
  const float* e2_W   = (const float*)d_in[7];
  const float* e2_b   = (const float*)d_in[8];
  const float* gat_W  = (const float*)d_in[9];
  const float* gat_al = (const float*)d_in[10];
  const float* gat_ar = (const float*)d_in[11];
  const float* gat_b  = (const float*)d_in[12];
  const float* attn_p = (const float*)d_in[13];
  const float* m1_W   = (const float*)d_in[14];
  const float* m1_b   = (const float*)d_in[15];
  const float* m_g    = (const float*)d_in[16];
  const float* m_bt   = (const float*)d_in[17];
  const float* m2_W   = (const float*)d_in[18];
  const float* m2_b   = (const float*)d_in[19];
  const float* d1_W   = (const float*)d_in[20];
  const float* d1_b   = (const float*)d_in[21];
  const float* d_g    = (const float*)d_in[22];
  const float* d_bt   = (const float*)d_in[23];
  const float* d2_W   = (const float*)d_in[24];
  const float* d2_b   = (const float*)d_in[25];

  float* ws = (float*)d_ws;
  size_t o = 0;
  float* h     = ws + o; o += (size_t)kN * kHID;
  float* bufA  = ws + o; o += (size_t)kN * kHID;
  float* bufB  = ws + o; o += (size_t)kN * kHID;
  float* vv    = ws + o; o += (size_t)kN * kHID;
  float* el    = ws + o; o += (size_t)kN * kH;
  float* er    = ws + o; o += (size_t)kN * kH;
  float* bnacc = ws + o; o += 4 * kHID;           // [sums][sumsqs][sc][sh]
  float* wsm   = ws + o; o += kR * kHID;
  float* cvec  = ws + o; o += kHID;
  int* rowptr  = (int*)(ws + o); o += (size_t)kR * (kN + 1);
  int* colidx  = (int*)(ws + o); o += (size_t)kR * kE;
  int* degcur  = (int*)(ws + o); o += (size_t)6 * kN;  // [deg 3N][cursor 3N]
  int* bsum    = (int*)(ws + o); o += kR * kSB;
  (void)ws_size; (void)in_sizes; (void)n_in; (void)out_size;

  int* deg    = degcur;
  int* cursor = degcur + 3 * kN;

  auto nb = [](long t) { return (int)((t + 255) / 256); };
  const long NH  = (long)kN * kHID;
  const long NHh = (long)kN * kH;
  const dim3 gE(nb(kE), kR);
  const dim3 gS(kSB, kR);
  const dim3 g128((kN + 127) / 128, 2);
  const dim3 g64((kN + 127) / 128, 1);
  const float invn = 1.0f / kN;
  float* F0 = nullptr; const float* cF0 = nullptr;

  // ---- CSR build, batched over relations ----
  hipMemsetAsync(degcur, 0, (size_t)6 * kN * sizeof(int), stream);
  hist_kernel<<<gE, 256, 0, stream>>>(dst, deg);
  bsum_kernel<<<gS, 256, 0, stream>>>(deg, bsum);
  bscan_kernel<<<1, 256, 0, stream>>>(bsum);
  scan2_kernel<<<gS, 256, 0, stream>>>(deg, bsum, rowptr);
  scatter_kernel<<<gE, 256, 0, stream>>>(src, dst, rowptr, cursor, colidx);

  // ---- embed MLP (skip=True) ----
  hipMemsetAsync(bnacc, 0, 2 * kHID * sizeof(float), stream);
  tgemm_kernel<<<g128, 256, 0, stream>>>(inputs, e1_W, e1_b, cF0, cF0, cF0, bnacc,
                                         cF0, cF0, F0, F0, bufA, kN, kIN, kHID);
  bnfold_kernel<<<1, kHID, 0, stream>>>(bnacc, e_g, e_bt, bnacc + 2 * kHID, bnacc + 3 * kHID, kHID, invn);
  bn_relu_kernel<<<nb(NH / 4), 256, 0, stream>>>(bufA, bnacc + 2 * kHID, bnacc + 3 * kHID, bufB, (int)(NH / 4), kHID);
  tgemm_kernel<<<g128, 256, 0, stream>>>(bufB, e2_W, e2_b, bufB, cF0, cF0, F0,
                                         cF0, cF0, F0, F0, h, kN, kHID, kHID);

  for (int l = 0; l < kL; l++) {
    wsoft_kernel<<<1, kHID, 0, stream>>>(attn_p + (size_t)l * kR * kHID,
                                         gat_b + (size_t)l * kR * kHID, wsm, cvec);
    for (int r = 0; r < kR; r++) {
      const float* W  = gat_W + ((size_t)(l * kR + r)) * kHID * kHID;
      const float* al = gat_al + (size_t)(l * kR + r) * kH * kFH;
      const float* ar = gat_ar + (size_t)(l * kR + r) * kH * kFH;
      tgemm_kernel<<<g128, 256, 0, stream>>>(h, W, cF0, cF0, cF0, cF0, F0,
                                             al, ar, el, er, bufA, kN, kHID, kHID);
      gat_fused_kernel<<<nb(NHh), 256, 0, stream>>>(rowptr + (size_t)r * (kN + 1),
                                                    colidx + (size_t)r * kE, bufA, el, er,
                                                    wsm + (size_t)r * kHID, cvec, vv, r == 0);
    }
    // layer MLP: m1 (stats fused) -> bnfold -> m2 (BN+ReLU fused on A, residual h)
    hipMemsetAsync(bnacc, 0, 2 * kHD2 * sizeof(float), stream);
    tgemm_kernel<<<g64, 256, 0, stream>>>(vv, m1_W + (size_t)l * kHID * kHD2,
                                          m1_b + (size_t)l * kHD2, cF0, cF0, cF0, bnacc,
                                          cF0, cF0, F0, F0, bufA, kN, kHID, kHD2);
    bnfold_kernel<<<1, kHD2, 0, stream>>>(bnacc, m_g + (size_t)l * kHD2, m_bt + (size_t)l * kHD2,
                                          bnacc + 2 * kHD2, bnacc + 3 * kHD2, kHD2, invn);
    tgemm_kernel<<<g128, 256, 0, stream>>>(bufA, m2_W + (size_t)l * kHD2 * kHID,
                                           m2_b + (size_t)l * kHID, h,
                                           bnacc + 2 * kHD2, bnacc + 3 * kHD2, F0,
                                           cF0, cF0, F0, F0, h, kN, kHD2, kHID);
  }

  // ---- decode MLP ----
  hipMemsetAsync(bnacc, 0, 2 * kHD2 * sizeof(float), stream);
  tgemm_kernel<<<g64, 256, 0, stream>>>(h, d1_W, d1_b, cF0, cF0, cF0, bnacc,
                                        cF0, cF0, F0, F0, bufA, kN, kHID, kHD2);
  bnfold_kernel<<<1, kHD2, 0, stream>>>(bnacc, d_g, d_bt, bnacc + 2 * kHD2, bnacc + 3 * kHD2, kHD2, invn);
  gemv_out_kernel<<<nb(kN), 256, 0, stream>>>(bufA, bnacc + 2 * kHD2, bnacc + 3 * kHD2,
                                              d2_W, d2_b, (float*)d_out, kN, kHD2);
}

// Round 5
// 394.367 us; speedup vs baseline: 11.4449x; 1.2344x over previous
//
#include <hip/hip_runtime.h>
#include <math.h>

// ---- problem constants ----
constexpr int kN   = 20000;
constexpr int kE   = 160000;
constexpr int kR   = 3;
constexpr int kL   = 2;
constexpr int kIN  = 64;
constexpr int kHID = 128;
constexpr int kH   = 16;
constexpr int kFH  = 8;
constexpr int kHD2 = 64;
constexpr int kSB  = (kN + 255) / 256;   // scan blocks per relation = 79

__device__ __forceinline__ ushort f2bf(float f) {  // RNE f32->bf16
  unsigned u = __float_as_uint(f);
  return (ushort)((u + 0x7fffu + ((u >> 16) & 1u)) >> 16);
}

// ---- generic tiled GEMM (f32 out) with fused epilogues ----
// BM=128, BN=64, BK=32, 256 threads, thread = 8 rows x 4 contiguous cols.
__global__ __launch_bounds__(256) void tgemm_kernel(
    const float* __restrict__ A, const float* __restrict__ W,
    const float* __restrict__ bias, const float* __restrict__ res,
    const float* __restrict__ bnsc, const float* __restrict__ bnsh,
    float* __restrict__ statS,
    float* __restrict__ C, int n, int k, int m) {
  constexpr int BM = 128, BN = 64, BK = 32, TM = 8, TN = 4;
  __shared__ float At[BK][BM];   // column-major A tile
  __shared__ float Wt[BK][BN];
  const int t  = threadIdx.x;
  const int tx = t & 15;
  const int ty = t >> 4;
  const int r0 = blockIdx.x * BM;
  const int c0 = blockIdx.y * BN;
  float acc[TM][TN] = {};
  for (int k0 = 0; k0 < k; k0 += BK) {
#pragma unroll
    for (int i = 0; i < 4; i++) {
      int li = t * 16 + i * 4;
      int row = li >> 5, col = li & 31;
      int gr = r0 + row;
      float4 v = make_float4(0.f, 0.f, 0.f, 0.f);
      if (gr < n) v = *(const float4*)&A[(size_t)gr * k + k0 + col];
      if (bnsc) {
        int c = k0 + col;
        v.x = fmaxf(fmaf(v.x, bnsc[c],     bnsh[c]),     0.f);
        v.y = fmaxf(fmaf(v.y, bnsc[c + 1], bnsh[c + 1]), 0.f);
        v.z = fmaxf(fmaf(v.z, bnsc[c + 2], bnsh[c + 2]), 0.f);
        v.w = fmaxf(fmaf(v.w, bnsc[c + 3], bnsh[c + 3]), 0.f);
      }
      At[col][row] = v.x; At[col + 1][row] = v.y;
      At[col + 2][row] = v.z; At[col + 3][row] = v.w;
    }
#pragma unroll
    for (int i = 0; i < 2; i++) {
      int li = t * 8 + i * 4;
      int row = li >> 6, col = li & 63;
      *(float4*)&Wt[row][col] = *(const float4*)&W[(size_t)(k0 + row) * m + c0 + col];
    }
    __syncthreads();
#pragma unroll
    for (int kk = 0; kk < BK; kk++) {
      float4 a0 = *(const float4*)&At[kk][ty * TM];
      float4 a1 = *(const float4*)&At[kk][ty * TM + 4];
      float4 w0 = *(const float4*)&Wt[kk][tx * TN];
      float a[TM] = {a0.x, a0.y, a0.z, a0.w, a1.x, a1.y, a1.z, a1.w};
      float w[TN] = {w0.x, w0.y, w0.z, w0.w};
#pragma unroll
      for (int i = 0; i < TM; i++)
#pragma unroll
        for (int j = 0; j < TN; j++) acc[i][j] = fmaf(a[i], w[j], acc[i][j]);
    }
    __syncthreads();
  }
#pragma unroll
  for (int i = 0; i < TM; i++) {
    int gr = r0 + ty * TM + i;
    if (gr < n) {
      int gc = c0 + tx * TN;
      float4 v = make_float4(acc[i][0], acc[i][1], acc[i][2], acc[i][3]);
      if (bias) { v.x += bias[gc]; v.y += bias[gc + 1]; v.z += bias[gc + 2]; v.w += bias[gc + 3]; }
      if (res) {
        float4 rr = *(const float4*)&res[(size_t)gr * m + gc];
        v.x += rr.x; v.y += rr.y; v.z += rr.z; v.w += rr.w;
      }
      *(float4*)&C[(size_t)gr * m + gc] = v;
      acc[i][0] = v.x; acc[i][1] = v.y; acc[i][2] = v.z; acc[i][3] = v.w;
    }
  }
  if (statS) {  // fused BatchNorm column statistics
    float s[TN] = {}, s2[TN] = {};
#pragma unroll
    for (int i = 0; i < TM; i++) {
      int gr = r0 + ty * TM + i;
      if (gr < n) {
#pragma unroll
        for (int j = 0; j < TN; j++) { float v = acc[i][j]; s[j] += v; s2[j] += v * v; }
      }
    }
    float* redS  = (float*)At;
    float* redS2 = redS + 1024;
#pragma unroll
    for (int j = 0; j < TN; j++) {
      redS[ty * 64 + tx * TN + j]  = s[j];
      redS2[ty * 64 + tx * TN + j] = s2[j];
    }
    __syncthreads();
    if (ty == 0) {
#pragma unroll
      for (int j = 0; j < TN; j++) {
        float ts = 0.f, ts2 = 0.f;
        for (int q = 0; q < 16; q++) { ts += redS[q * 64 + tx * TN + j]; ts2 += redS2[q * 64 + tx * TN + j]; }
        atomicAdd(&statS[c0 + tx * TN + j], ts);
        atomicAdd(&statS[m + c0 + tx * TN + j], ts2);
      }
    }
  }
}

// ---- z-GEMM, batched over relations (blockIdx.z = r): bf16 z out + el/er epilogue ----
__global__ __launch_bounds__(256) void zgemm_kernel(
    const float* __restrict__ A, const float* __restrict__ Wbase,
    const float* __restrict__ albase, const float* __restrict__ arbase,
    ushort* __restrict__ z, float* __restrict__ el, float* __restrict__ er, int n) {
  constexpr int BM = 128, BN = 64, BK = 32, TM = 8, TN = 4;
  const int r = blockIdx.z;
  const float* W  = Wbase + (size_t)r * kHID * kHID;
  const float* al = albase + (size_t)r * kH * kFH;
  const float* ar = arbase + (size_t)r * kH * kFH;
  ushort* zr = z + (size_t)r * kN * kHID;
  float* elr = el + (size_t)r * kN * kH;
  float* err = er + (size_t)r * kN * kH;
  __shared__ float At[BK][BM];
  __shared__ float Wt[BK][BN];
  const int t  = threadIdx.x;
  const int tx = t & 15;
  const int ty = t >> 4;
  const int r0 = blockIdx.x * BM;
  const int c0 = blockIdx.y * BN;
  float acc[TM][TN] = {};
  for (int k0 = 0; k0 < kHID; k0 += BK) {
#pragma unroll
    for (int i = 0; i < 4; i++) {
      int li = t * 16 + i * 4;
      int row = li >> 5, col = li & 31;
      int gr = r0 + row;
      float4 v = make_float4(0.f, 0.f, 0.f, 0.f);
      if (gr < n) v = *(const float4*)&A[(size_t)gr * kHID + k0 + col];
      At[col][row] = v.x; At[col + 1][row] = v.y;
      At[col + 2][row] = v.z; At[col + 3][row] = v.w;
    }
#pragma unroll
    for (int i = 0; i < 2; i++) {
      int li = t * 8 + i * 4;
      int row = li >> 6, col = li & 63;
      *(float4*)&Wt[row][col] = *(const float4*)&W[(size_t)(k0 + row) * kHID + c0 + col];
    }
    __syncthreads();
#pragma unroll
    for (int kk = 0; kk < BK; kk++) {
      float4 a0 = *(const float4*)&At[kk][ty * TM];
      float4 a1 = *(const float4*)&At[kk][ty * TM + 4];
      float4 w0 = *(const float4*)&Wt[kk][tx * TN];
      float a[TM] = {a0.x, a0.y, a0.z, a0.w, a1.x, a1.y, a1.z, a1.w};
      float w[TN] = {w0.x, w0.y, w0.z, w0.w};
#pragma unroll
      for (int i = 0; i < TM; i++)
#pragma unroll
        for (int j = 0; j < TN; j++) acc[i][j] = fmaf(a[i], w[j], acc[i][j]);
    }
    __syncthreads();
  }
  // bf16 z store
#pragma unroll
  for (int i = 0; i < TM; i++) {
    int gr = r0 + ty * TM + i;
    if (gr < n) {
      ushort4 sv;
      sv.x = f2bf(acc[i][0]); sv.y = f2bf(acc[i][1]);
      sv.z = f2bf(acc[i][2]); sv.w = f2bf(acc[i][3]);
      *(ushort4*)&zr[(size_t)gr * kHID + c0 + tx * TN] = sv;
    }
  }
  // el/er epilogue: this thread's 4 cols are half of one head
  int hd  = (c0 >> 3) + (tx >> 1);
  int ofs = (tx & 1) * 4;
  float alv[TN], arv[TN];
#pragma unroll
  for (int j = 0; j < TN; j++) { alv[j] = al[hd * kFH + ofs + j]; arv[j] = ar[hd * kFH + ofs + j]; }
#pragma unroll
  for (int i = 0; i < TM; i++) {
    int gr = r0 + ty * TM + i;
    float pl = acc[i][0] * alv[0] + acc[i][1] * alv[1] + acc[i][2] * alv[2] + acc[i][3] * alv[3];
    float pr = acc[i][0] * arv[0] + acc[i][1] * arv[1] + acc[i][2] * arv[2] + acc[i][3] * arv[3];
    pl += __shfl_xor(pl, 1, 64);
    pr += __shfl_xor(pr, 1, 64);
    if (!(tx & 1) && gr < n) { elr[gr * kH + hd] = pl; err[gr * kH + hd] = pr; }
  }
}

// ---- fold BN stats into scale/shift ----
__global__ void bnfold_kernel(const float* __restrict__ statS, const float* __restrict__ g,
                              const float* __restrict__ bt, float* __restrict__ sc,
                              float* __restrict__ sh, int dim, float invn) {
  int c = threadIdx.x;
  if (c >= dim) return;
  float mu  = statS[c] * invn;
  float var = statS[dim + c] * invn - mu * mu;
  float s = g[c] * rsqrtf(var + 1e-5f);
  sc[c] = s; sh[c] = bt[c] - mu * s;
}

// ---- BN apply + ReLU (embed only) ----
__global__ void bn_relu_kernel(const float* __restrict__ X, const float* __restrict__ sc,
                               const float* __restrict__ sh, float* __restrict__ Y,
                               int total4, int m) {
  int i4 = blockIdx.x * 256 + threadIdx.x;
  if (i4 >= total4) return;
  int c = (i4 * 4) % m;
  float4 x = ((const float4*)X)[i4];
  float4 y;
  y.x = fmaxf(fmaf(x.x, sc[c],     sh[c]),     0.f);
  y.y = fmaxf(fmaf(x.y, sc[c + 1], sh[c + 1]), 0.f);
  y.z = fmaxf(fmaf(x.z, sc[c + 2], sh[c + 2]), 0.f);
  y.w = fmaxf(fmaf(x.w, sc[c + 3], sh[c + 3]), 0.f);
  ((float4*)Y)[i4] = y;
}

// ---- CSR build (batched over relations via blockIdx.y) ----
__global__ void hist_kernel(const int* __restrict__ dst, int* __restrict__ deg) {
  int r = blockIdx.y;
  int e = blockIdx.x * 256 + threadIdx.x;
  if (e < kE) atomicAdd(&deg[r * kN + dst[r * kE + e]], 1);
}

__global__ void bsum_kernel(const int* __restrict__ deg, int* __restrict__ bsum) {
  int r = blockIdx.y;
  int j = blockIdx.x * 256 + threadIdx.x;
  int x = (j < kN) ? deg[r * kN + j] : 0;
  __shared__ int shm[256];
  shm[threadIdx.x] = x;
  __syncthreads();
  for (int off = 128; off > 0; off >>= 1) {
    if (threadIdx.x < off) shm[threadIdx.x] += shm[threadIdx.x + off];
    __syncthreads();
  }
  if (threadIdx.x == 0) bsum[r * kSB + blockIdx.x] = shm[0];
}

__global__ void bscan_kernel(int* __restrict__ bsum) {
  __shared__ int shm[kR * kSB];
  int t = threadIdx.x;
  for (int i = t; i < kR * kSB; i += 256) shm[i] = bsum[i];
  __syncthreads();
  if (t < kR) {
    int run = 0;
    for (int b = 0; b < kSB; b++) { int v = shm[t * kSB + b]; shm[t * kSB + b] = run; run += v; }
  }
  __syncthreads();
  for (int i = t; i < kR * kSB; i += 256) bsum[i] = shm[i];
}

__global__ void scan2_kernel(const int* __restrict__ deg, const int* __restrict__ bsum,
                             int* __restrict__ rowptr) {
  int r = blockIdx.y;
  int t = threadIdx.x;
  int j = blockIdx.x * 256 + t;
  int x = (j < kN) ? deg[r * kN + j] : 0;
  int lane = t & 63, w = t >> 6;
  int v = x;
  for (int off = 1; off < 64; off <<= 1) {
    int y = __shfl_up(v, off, 64);
    if (lane >= off) v += y;
  }
  __shared__ int wtot[4];
  if (lane == 63) wtot[w] = v;
  __syncthreads();
  int add = bsum[r * kSB + blockIdx.x];
  for (int i = 0; i < 4; i++) if (i < w) add += wtot[i];
  if (j < kN) rowptr[r * (kN + 1) + j] = add + v - x;
  if (blockIdx.x == 0 && t == 0) rowptr[r * (kN + 1) + kN] = kE;
}

__global__ void scatter_kernel(const int* __restrict__ src, const int* __restrict__ dst,
                               const int* __restrict__ rowptr, int* __restrict__ cursor,
                               int* __restrict__ col) {
  int r = blockIdx.y;
  int e = blockIdx.x * 256 + threadIdx.x;
  if (e < kE) {
    int d = dst[r * kE + e];
    int p = atomicAdd(&cursor[r * kN + d], 1);
    col[r * kE + rowptr[r * (kN + 1) + d] + p] = src[r * kE + e];
  }
}

// ---- fused edge softmax + aggregation over ALL relations: thread per (dst,head) ----
__global__ void gat3_kernel(const int* __restrict__ rowptr, const int* __restrict__ colidx,
                            const ushort* __restrict__ z, const float* __restrict__ el,
                            const float* __restrict__ er, const float* __restrict__ wsm,
                            const float* __restrict__ cvec, float* __restrict__ vv) {
  int idx = blockIdx.x * 256 + threadIdx.x;
  if (idx >= kN * kH) return;
  int d = idx >> 4, hh = idx & 15;
  float out[kFH];
  const float* cv = cvec + (hh << 3);
#pragma unroll
  for (int f = 0; f < kFH; f++) out[f] = cv[f];
  for (int r = 0; r < kR; r++) {
    const int* rp = rowptr + r * (kN + 1);
    const int* ci = colidx + (size_t)r * kE;
    const ushort* zr = z + (size_t)r * kN * kHID;
    const float* elr = el + (size_t)r * kN * kH;
    float erd = er[(size_t)r * kN * kH + (d << 4) + hh];
    int beg = rp[d], end = rp[d + 1];
    float s = 0.f;
    float acc[kFH] = {};
    for (int p = beg; p < end; p++) {
      int sv = ci[p];
      float v = elr[(sv << 4) + hh] + erd;
      v = v > 0.f ? v : 0.2f * v;
      float ex = __expf(v);   // logits O(0.1): no overflow, identical softmax
      s += ex;
      uint4 zz = *(const uint4*)(zr + ((size_t)sv << 7) + (hh << 3));
      acc[0] = fmaf(ex, __uint_as_float(zz.x << 16),        acc[0]);
      acc[1] = fmaf(ex, __uint_as_float(zz.x & 0xffff0000u), acc[1]);
      acc[2] = fmaf(ex, __uint_as_float(zz.y << 16),        acc[2]);
      acc[3] = fmaf(ex, __uint_as_float(zz.y & 0xffff0000u), acc[3]);
      acc[4] = fmaf(ex, __uint_as_float(zz.z << 16),        acc[4]);
      acc[5] = fmaf(ex, __uint_as_float(zz.z & 0xffff0000u), acc[5]);
      acc[6] = fmaf(ex, __uint_as_float(zz.w << 16),        acc[6]);
      acc[7] = fmaf(ex, __uint_as_float(zz.w & 0xffff0000u), acc[7]);
    }
    float inv = s > 0.f ? 1.f / s : 0.f;
    const float* wp = wsm + r * kHID + (hh << 3);
#pragma unroll
    for (int f = 0; f < kFH; f++) out[f] = fmaf(wp[f] * inv, acc[f], out[f]);
  }
  float4* vp = (float4*)(vv + ((size_t)d << 7) + (hh << 3));
  vp[0] = make_float4(out[0], out[1], out[2], out[3]);
  vp[1] = make_float4(out[4], out[5], out[6], out[7]);
}

// ---- relation softmax weights + folded bias ----
__global__ void wsoft_kernel(const float* __restrict__ p, const float* __restrict__ b,
                             float* __restrict__ w, float* __restrict__ c) {
  int f = threadIdx.x;  // 128 threads
  float p0 = p[f], p1 = p[kHID + f], p2 = p[2 * kHID + f];
  float mx = fmaxf(p0, fmaxf(p1, p2));
  float e0 = __expf(p0 - mx), e1 = __expf(p1 - mx), e2 = __expf(p2 - mx);
  float s = e0 + e1 + e2;
  float w0 = e0 / s, w1 = e1 / s, w2 = e2 / s;
  w[f] = w0; w[kHID + f] = w1; w[2 * kHID + f] = w2;
  c[f] = w0 * b[f] + w1 * b[kHID + f] + w2 * b[2 * kHID + f];
}

// ---- final gemv with fused BN+ReLU on input ----
__global__ void gemv_out_kernel(const float* __restrict__ A, const float* __restrict__ sc,
                                const float* __restrict__ sh, const float* __restrict__ w,
                                const float* __restrict__ b, float* __restrict__ out,
                                int n, int k) {
  int i = blockIdx.x * 256 + threadIdx.x;
  if (i >= n) return;
  const float4* a = (const float4*)(A + (size_t)i * k);
  float acc = b[0];
  for (int j4 = 0; j4 < k / 4; j4++) {
    float4 x = a[j4];
    int c = j4 * 4;
    acc = fmaf(fmaxf(fmaf(x.x, sc[c],     sh[c]),     0.f), w[c],     acc);
    acc = fmaf(fmaxf(fmaf(x.y, sc[c + 1], sh[c + 1]), 0.f), w[c + 1], acc);
    acc = fmaf(fmaxf(fmaf(x.z, sc[c + 2], sh[c + 2]), 0.f), w[c + 2], acc);
    acc = fmaf(fmaxf(fmaf(x.w, sc[c + 3], sh[c + 3]), 0.f), w[c + 3], acc);
  }
  out[i] = acc;
}

extern "C" void kernel_launch(void* const* d_in, const int* in_sizes, int n_in,
                              void* d_out, int out_size, void* d_ws, size_t ws_size,
                              hipStream_t stream) {
  const float* inputs = (const float*)d_in[0];
  const int*   src    = (const int*)d_in[1];
  const int*   dst    = (const int*)d_in[2];
  const float* e1_W   = (const float*)d_in[3];
  const float* e1_b   = (const float*)d_in[4];
  const float* e_g    = (const float*)d_in[5];
  const float* e_bt   = (const float*)d_in[6];
  const float* e2_W   = (const float*)d_in[7];
  const float* e2_b   = (const float*)d_in[8];
  const float* gat_W  = (const float*)d_in[9];
  const float* gat_al = (const float*)d_in[10];
  const float* gat_ar = (const float*)d_in[11];
  const float* gat_b  = (const float*)d_in[12];
  const float* attn_p = (const float*)d_in[13];
  const float* m1_W   = (const float*)d_in[14];
  const float* m1_b   = (const float*)d_in[15];
  const float* m_g    = (const float*)d_in[16];
  const float* m_bt   = (const float*)d_in[17];
  const float* m2_W   = (const float*)d_in[18];
  const float* m2_b   = (const float*)d_in[19];
  const float* d1_W   = (const float*)d_in[20];
  const float* d1_b   = (const float*)d_in[21];
  const float* d_g    = (const float*)d_in[22];
  const float* d_bt   = (const float*)d_in[23];
  const float* d2_W   = (const float*)d_in[24];
  const float* d2_b   = (const float*)d_in[25];

  float* ws = (float*)d_ws;
  size_t o = 0;
  float* h     = ws + o; o += (size_t)kN * kHID;
  float* bufA  = ws + o; o += (size_t)kN * kHID;
  float* bufB  = ws + o; o += (size_t)kN * kHID;
  float* vv    = ws + o; o += (size_t)kN * kHID;
  ushort* z    = (ushort*)(ws + o); o += (size_t)kR * kN * kHID / 2;  // bf16 [R][N][HID]
  float* el    = ws + o; o += (size_t)kR * kN * kH;
  float* er    = ws + o; o += (size_t)kR * kN * kH;
  float* bnacc = ws + o; o += 4 * kHID;           // [sums][sumsqs][sc][sh]
  float* wsm   = ws + o; o += kR * kHID;
  float* cvec  = ws + o; o += kHID;
  int* rowptr  = (int*)(ws + o); o += (size_t)kR * (kN + 1);
  int* colidx  = (int*)(ws + o); o += (size_t)kR * kE;
  int* degcur  = (int*)(ws + o); o += (size_t)6 * kN;  // [deg 3N][cursor 3N]
  int* bsum    = (int*)(ws + o); o += kR * kSB;
  (void)ws_size; (void)in_sizes; (void)n_in; (void)out_size;

  int* deg    = degcur;
  int* cursor = degcur + 3 * kN;

  auto nb = [](long t) { return (int)((t + 255) / 256); };
  const long NH  = (long)kN * kHID;
  const long NHh = (long)kN * kH;
  const dim3 gE(nb(kE), kR);
  const dim3 gS(kSB, kR);
  const dim3 g128((kN + 127) / 128, 2);
  const dim3 g64((kN + 127) / 128, 1);
  const dim3 gZ((kN + 127) / 128, 2, kR);
  const float invn = 1.0f / kN;
  float* F0 = nullptr; const float* cF0 = nullptr;

  // ---- CSR build, batched over relations ----
  hipMemsetAsync(degcur, 0, (size_t)6 * kN * sizeof(int), stream);
  hist_kernel<<<gE, 256, 0, stream>>>(dst, deg);
  bsum_kernel<<<gS, 256, 0, stream>>>(deg, bsum);
  bscan_kernel<<<1, 256, 0, stream>>>(bsum);
  scan2_kernel<<<gS, 256, 0, stream>>>(deg, bsum, rowptr);
  scatter_kernel<<<gE, 256, 0, stream>>>(src, dst, rowptr, cursor, colidx);

  // ---- embed MLP (skip=True) ----
  hipMemsetAsync(bnacc, 0, 2 * kHID * sizeof(float), stream);
  tgemm_kernel<<<g128, 256, 0, stream>>>(inputs, e1_W, e1_b, cF0, cF0, cF0, bnacc,
                                         bufA, kN, kIN, kHID);
  bnfold_kernel<<<1, kHID, 0, stream>>>(bnacc, e_g, e_bt, bnacc + 2 * kHID, bnacc + 3 * kHID, kHID, invn);
  bn_relu_kernel<<<nb(NH / 4), 256, 0, stream>>>(bufA, bnacc + 2 * kHID, bnacc + 3 * kHID, bufB, (int)(NH / 4), kHID);
  tgemm_kernel<<<g128, 256, 0, stream>>>(bufB, e2_W, e2_b, bufB, cF0, cF0, F0,
                                         h, kN, kHID, kHID);

  for (int l = 0; l < kL; l++) {
    wsoft_kernel<<<1, kHID, 0, stream>>>(attn_p + (size_t)l * kR * kHID,
                                         gat_b + (size_t)l * kR * kHID, wsm, cvec);
    zgemm_kernel<<<gZ, 256, 0, stream>>>(h, gat_W + (size_t)l * kR * kHID * kHID,
                                         gat_al + (size_t)l * kR * kH * kFH,
                                         gat_ar + (size_t)l * kR * kH * kFH,
                                         z, el, er, kN);
    gat3_kernel<<<nb(NHh), 256, 0, stream>>>(rowptr, colidx, z, el, er, wsm, cvec, vv);
    // layer MLP: m1 (stats fused) -> bnfold -> m2 (BN+ReLU fused on A, residual h)
    hipMemsetAsync(bnacc, 0, 2 * kHD2 * sizeof(float), stream);
    tgemm_kernel<<<g64, 256, 0, stream>>>(vv, m1_W + (size_t)l * kHID * kHD2,
                                          m1_b + (size_t)l * kHD2, cF0, cF0, cF0, bnacc,
                                          bufA, kN, kHID, kHD2);
    bnfold_kernel<<<1, kHD2, 0, stream>>>(bnacc, m_g + (size_t)l * kHD2, m_bt + (size_t)l * kHD2,
                                          bnacc + 2 * kHD2, bnacc + 3 * kHD2, kHD2, invn);
    tgemm_kernel<<<g128, 256, 0, stream>>>(bufA, m2_W + (size_t)l * kHD2 * kHID,
                                           m2_b + (size_t)l * kHID, h,
                                           bnacc + 2 * kHD2, bnacc + 3 * kHD2, F0,
                                           h, kN, kHD2, kHID);
  }

  // ---- decode MLP ----
  hipMemsetAsync(bnacc, 0, 2 * kHD2 * sizeof(float), stream);
  tgemm_kernel<<<g64, 256, 0, stream>>>(h, d1_W, d1_b, cF0, cF0, cF0, bnacc,
                                        bufA, kN, kHID, kHD2);
  bnfold_kernel<<<1, kHD2, 0, stream>>>(bnacc, d_g, d_bt, bnacc + 2 * kHD2, bnacc + 3 * kHD2, kHD2, invn);
  gemv_out_kernel<<<nb(kN), 256, 0, stream>>>(bufA, bnacc + 2 * kHD2, bnacc + 3 * kHD2,
                                              d2_W, d2_b, (float*)d_out, kN, kHD2);
}

// Round 6
// 386.412 us; speedup vs baseline: 11.6805x; 1.0206x over previous
//
#include <hip/hip_runtime.h>
#include <math.h>

// ---- problem constants ----
constexpr int kN   = 20000;
constexpr int kE   = 160000;
constexpr int kR   = 3;
constexpr int kL   = 2;
constexpr int kIN  = 64;
constexpr int kHID = 128;
constexpr int kH   = 16;
constexpr int kFH  = 8;
constexpr int kHD2 = 64;
constexpr int kSB  = (kN + 255) / 256;   // scan blocks per relation = 79

typedef __bf16 bf16x8 __attribute__((ext_vector_type(8)));
typedef float  f32x4  __attribute__((ext_vector_type(4)));

__device__ __forceinline__ bf16x8 ldfrag(const __bf16* p) {
  return __builtin_bit_cast(bf16x8, *(const uint4*)p);
}
__device__ __forceinline__ f32x4 MF(bf16x8 a, bf16x8 b, f32x4 c) {
  return __builtin_amdgcn_mfma_f32_16x16x32_bf16(a, b, c, 0, 0, 0);
}

// ============================================================================
// MFMA GEMM, 3-pass bf16 split (~f32 precision): C = A @ W (+bias)(+res)
// A given as hi/lo bf16 [n][k]; W given transposed+split: WT[m][k] hi then lo.
// BM=128 (4 waves x 32 rows), BN=64 (4 col-frags/wave), K in {64,128}.
// Epilogues: bias, res (f32 or bf16-pair), BN col stats, outs f32 / bf16 hi/lo.
// ============================================================================
__global__ __launch_bounds__(256) void mgemm_kernel(
    const __bf16* __restrict__ Ahi, const __bf16* __restrict__ Alo,
    const __bf16* __restrict__ WT,
    const float* __restrict__ bias,
    const float* __restrict__ resf,
    const __bf16* __restrict__ resh, const __bf16* __restrict__ resl,
    float* __restrict__ statS,
    float* __restrict__ Cf, __bf16* __restrict__ Chi, __bf16* __restrict__ Clo,
    int n, int k, int m, long wstride, long cstride) {
  __shared__ __bf16 Bh[64][136];   // +8 bf16 pad: stride 272B -> conflict-free frags
  __shared__ __bf16 Bl[64][136];
  const int t  = threadIdx.x;
  const int w  = t >> 6;           // wave 0..3
  const int l  = t & 63;
  const int lr = l & 15;
  const int lg = l >> 4;           // 0..3
  const int rb = blockIdx.x * 128 + w * 32;
  const int c0 = blockIdx.y * 64;
  const __bf16* Whi = WT + (size_t)blockIdx.z * wstride;
  const __bf16* Wlo = Whi + (size_t)k * m;
  if (Chi) Chi += (size_t)blockIdx.z * cstride;

  const int kseg = k >> 3;
  for (int idx = t; idx < 64 * kseg; idx += 256) {
    int col = idx / kseg, seg = idx - col * kseg;
    *(uint4*)&Bh[col][seg * 8] = *(const uint4*)&Whi[(size_t)(c0 + col) * k + seg * 8];
    *(uint4*)&Bl[col][seg * 8] = *(const uint4*)&Wlo[(size_t)(c0 + col) * k + seg * 8];
  }
  __syncthreads();

  int r0 = rb + lr;      if (r0 > n - 1) r0 = n - 1;
  int r1 = rb + 16 + lr; if (r1 > n - 1) r1 = n - 1;
  f32x4 acc[2][4] = {};

  for (int ks = 0; ks < (k >> 5); ks++) {
    const int koff = ks * 32 + lg * 8;
    bf16x8 a0h = ldfrag(&Ahi[(size_t)r0 * k + koff]);
    bf16x8 a0l = ldfrag(&Alo[(size_t)r0 * k + koff]);
    bf16x8 a1h = ldfrag(&Ahi[(size_t)r1 * k + koff]);
    bf16x8 a1l = ldfrag(&Alo[(size_t)r1 * k + koff]);
#pragma unroll
    for (int j = 0; j < 4; j++) {
      bf16x8 bh = ldfrag(&Bh[j * 16 + lr][koff]);
      bf16x8 bl = ldfrag(&Bl[j * 16 + lr][koff]);
      acc[0][j] = MF(a0h, bh, acc[0][j]);
      acc[0][j] = MF(a0l, bh, acc[0][j]);
      acc[0][j] = MF(a0h, bl, acc[0][j]);
      acc[1][j] = MF(a1h, bh, acc[1][j]);
      acc[1][j] = MF(a1l, bh, acc[1][j]);
      acc[1][j] = MF(a1h, bl, acc[1][j]);
    }
  }

  // epilogue: D element (i,j,q) -> row rb+i*16+lg*4+q, col c0+j*16+lr
  float s[4] = {}, s2[4] = {};
#pragma unroll
  for (int i = 0; i < 2; i++) {
#pragma unroll
    for (int q = 0; q < 4; q++) {
      int row = rb + i * 16 + lg * 4 + q;
      bool ok = row < n;
#pragma unroll
      for (int j = 0; j < 4; j++) {
        int col = c0 + j * 16 + lr;
        float v = acc[i][j][q];
        if (bias) v += bias[col];
        size_t off = (size_t)row * m + col;
        if (ok) {
          if (resf) v += resf[off];
          if (resh) v += (float)resh[off] + (float)resl[off];
          if (Cf) Cf[off] = v;
          if (Chi) {
            __bf16 hb = (__bf16)v;
            Chi[off] = hb;
            if (Clo) Clo[off] = (__bf16)(v - (float)hb);
          }
          s[j] += v; s2[j] += v * v;
        }
      }
    }
  }
  if (statS) {
    __syncthreads();
    float* red = (float*)&Bh[0][0];   // 512 floats scratch
#pragma unroll
    for (int j = 0; j < 4; j++) {
      float a = s[j], b = s2[j];
      a += __shfl_xor(a, 16, 64); a += __shfl_xor(a, 32, 64);
      b += __shfl_xor(b, 16, 64); b += __shfl_xor(b, 32, 64);
      if (lg == 0) { red[w * 64 + j * 16 + lr] = a; red[256 + w * 64 + j * 16 + lr] = b; }
    }
    __syncthreads();
    if (t < 64) {
      float a = red[t] + red[64 + t] + red[128 + t] + red[192 + t];
      float b = red[256 + t] + red[320 + t] + red[384 + t] + red[448 + t];
      atomicAdd(&statS[c0 + t], a);
      atomicAdd(&statS[m + c0 + t], b);
    }
  }
}

// ---- weight transpose + bf16 hi/lo split prep ----
struct WDesc { const float* src; long doff; int k, m; };
struct WDescs { WDesc d[13]; };
__global__ void wprep_kernel(WDescs ds, __bf16* __restrict__ wt) {
  WDesc dd = ds.d[blockIdx.y];
  int idx = blockIdx.x * 256 + threadIdx.x;
  if (idx >= dd.k * dd.m) return;
  int row = idx / dd.m, col = idx - row * dd.m;   // src [k][m] row-major
  float v = dd.src[idx];
  __bf16 hb = (__bf16)v;
  __bf16 lb = (__bf16)(v - (float)hb);
  wt[dd.doff + (size_t)col * dd.k + row] = hb;
  wt[dd.doff + (size_t)dd.k * dd.m + (size_t)col * dd.k + row] = lb;
}

// ---- elW prep: elW[l][k][r*32+hd*2+side] = sum_f W[l,r][k][hd*8+f]*a{l,r}[hd][f] ----
__global__ void elw_kernel(const float* __restrict__ gat_W, const float* __restrict__ gat_al,
                           const float* __restrict__ gat_ar, float* __restrict__ elW) {
  int idx = blockIdx.x * 256 + threadIdx.x;   // 2*128*128
  int ll = idx >> 14, kk = (idx >> 7) & 127, c = idx & 127;
  float v = 0.f;
  if (c < 96) {
    int r = c >> 5, hd = (c >> 1) & 15, side = c & 1;
    const float* Wp = gat_W + ((size_t)(ll * 3 + r) << 14) + kk * 128 + (hd << 3);
    const float* ap = (side ? gat_ar : gat_al) + ((size_t)(ll * 3 + r) << 7) + (hd << 3);
#pragma unroll
    for (int f = 0; f < kFH; f++) v += Wp[f] * ap[f];
  }
  elW[idx] = v;
}

// ---- f32 tiled GEMM (used for el/er logits only) ----
__global__ __launch_bounds__(256) void tgemm_kernel(
    const float* __restrict__ A, const float* __restrict__ W,
    float* __restrict__ C, int n, int k, int m) {
  constexpr int BM = 128, BN = 64, BK = 32, TM = 8, TN = 4;
  __shared__ float At[BK][BM];
  __shared__ float Wt[BK][BN];
  const int t  = threadIdx.x;
  const int tx = t & 15;
  const int ty = t >> 4;
  const int r0 = blockIdx.x * BM;
  const int c0 = blockIdx.y * BN;
  float acc[TM][TN] = {};
  for (int k0 = 0; k0 < k; k0 += BK) {
#pragma unroll
    for (int i = 0; i < 4; i++) {
      int li = t * 16 + i * 4;
      int row = li >> 5, col = li & 31;
      int gr = r0 + row;
      float4 v = make_float4(0.f, 0.f, 0.f, 0.f);
      if (gr < n) v = *(const float4*)&A[(size_t)gr * k + k0 + col];
      At[col][row] = v.x; At[col + 1][row] = v.y;
      At[col + 2][row] = v.z; At[col + 3][row] = v.w;
    }
#pragma unroll
    for (int i = 0; i < 2; i++) {
      int li = t * 8 + i * 4;
      int row = li >> 6, col = li & 63;
      *(float4*)&Wt[row][col] = *(const float4*)&W[(size_t)(k0 + row) * m + c0 + col];
    }
    __syncthreads();
#pragma unroll
    for (int kk = 0; kk < BK; kk++) {
      float4 a0 = *(const float4*)&At[kk][ty * TM];
      float4 a1 = *(const float4*)&At[kk][ty * TM + 4];
      float4 w0 = *(const float4*)&Wt[kk][tx * TN];
      float a[TM] = {a0.x, a0.y, a0.z, a0.w, a1.x, a1.y, a1.z, a1.w};
      float w[TN] = {w0.x, w0.y, w0.z, w0.w};
#pragma unroll
      for (int i = 0; i < TM; i++)
#pragma unroll
        for (int j = 0; j < TN; j++) acc[i][j] = fmaf(a[i], w[j], acc[i][j]);
    }
    __syncthreads();
  }
#pragma unroll
  for (int i = 0; i < TM; i++) {
    int gr = r0 + ty * TM + i;
    if (gr < n)
      *(float4*)&C[(size_t)gr * m + c0 + tx * TN] =
          make_float4(acc[i][0], acc[i][1], acc[i][2], acc[i][3]);
  }
}

// ---- fold BN stats into scale/shift ----
__global__ void bnfold_kernel(const float* __restrict__ statS, const float* __restrict__ g,
                              const float* __restrict__ bt, float* __restrict__ sc,
                              float* __restrict__ sh, int dim, float invn) {
  int c = threadIdx.x;
  if (c >= dim) return;
  float mu  = statS[c] * invn;
  float var = statS[dim + c] * invn - mu * mu;
  float s = g[c] * rsqrtf(var + 1e-5f);
  sc[c] = s; sh[c] = bt[c] - mu * s;
}

// ---- split to bf16 hi/lo, optional fused BN+ReLU ----
__global__ void split_kernel(const float* __restrict__ X, const float* __restrict__ sc,
                             const float* __restrict__ sh, __bf16* __restrict__ hi,
                             __bf16* __restrict__ lo, int total4, int m) {
  int i4 = blockIdx.x * 256 + threadIdx.x;
  if (i4 >= total4) return;
  float4 x = ((const float4*)X)[i4];
  float y0 = x.x, y1 = x.y, y2 = x.z, y3 = x.w;
  if (sc) {
    int c = (i4 * 4) % m;
    y0 = fmaxf(fmaf(y0, sc[c],     sh[c]),     0.f);
    y1 = fmaxf(fmaf(y1, sc[c + 1], sh[c + 1]), 0.f);
    y2 = fmaxf(fmaf(y2, sc[c + 2], sh[c + 2]), 0.f);
    y3 = fmaxf(fmaf(y3, sc[c + 3], sh[c + 3]), 0.f);
  }
  union { __bf16 b[4]; uint2 u; } uh, ul;
  uh.b[0] = (__bf16)y0; ul.b[0] = (__bf16)(y0 - (float)uh.b[0]);
  uh.b[1] = (__bf16)y1; ul.b[1] = (__bf16)(y1 - (float)uh.b[1]);
  uh.b[2] = (__bf16)y2; ul.b[2] = (__bf16)(y2 - (float)uh.b[2]);
  uh.b[3] = (__bf16)y3; ul.b[3] = (__bf16)(y3 - (float)uh.b[3]);
  ((uint2*)hi)[i4] = uh.u;
  ((uint2*)lo)[i4] = ul.u;
}

// ---- CSR build (batched over relations via blockIdx.y) ----
__global__ void hist_kernel(const int* __restrict__ dst, int* __restrict__ deg) {
  int r = blockIdx.y;
  int e = blockIdx.x * 256 + threadIdx.x;
  if (e < kE) atomicAdd(&deg[r * kN + dst[r * kE + e]], 1);
}

__global__ void bsum_kernel(const int* __restrict__ deg, int* __restrict__ bsum) {
  int r = blockIdx.y;
  int j = blockIdx.x * 256 + threadIdx.x;
  int x = (j < kN) ? deg[r * kN + j] : 0;
  __shared__ int shm[256];
  shm[threadIdx.x] = x;
  __syncthreads();
  for (int off = 128; off > 0; off >>= 1) {
    if (threadIdx.x < off) shm[threadIdx.x] += shm[threadIdx.x + off];
    __syncthreads();
  }
  if (threadIdx.x == 0) bsum[r * kSB + blockIdx.x] = shm[0];
}

__global__ void bscan_kernel(int* __restrict__ bsum) {
  __shared__ int shm[kR * kSB];
  int t = threadIdx.x;
  for (int i = t; i < kR * kSB; i += 256) shm[i] = bsum[i];
  __syncthreads();
  if (t < kR) {
    int run = 0;
    for (int b = 0; b < kSB; b++) { int v = shm[t * kSB + b]; shm[t * kSB + b] = run; run += v; }
  }
  __syncthreads();
  for (int i = t; i < kR * kSB; i += 256) bsum[i] = shm[i];
}

__global__ void scan2_kernel(const int* __restrict__ deg, const int* __restrict__ bsum,
                             int* __restrict__ rowptr) {
  int r = blockIdx.y;
  int t = threadIdx.x;
  int j = blockIdx.x * 256 + t;
  int x = (j < kN) ? deg[r * kN + j] : 0;
  int lane = t & 63, w = t >> 6;
  int v = x;
  for (int off = 1; off < 64; off <<= 1) {
    int y = __shfl_up(v, off, 64);
    if (lane >= off) v += y;
  }
  __shared__ int wtot[4];
  if (lane == 63) wtot[w] = v;
  __syncthreads();
  int add = bsum[r * kSB + blockIdx.x];
  for (int i = 0; i < 4; i++) if (i < w) add += wtot[i];
  if (j < kN) rowptr[r * (kN + 1) + j] = add + v - x;
  if (blockIdx.x == 0 && t == 0) rowptr[r * (kN + 1) + kN] = kE;
}

__global__ void scatter_kernel(const int* __restrict__ src, const int* __restrict__ dst,
                               const int* __restrict__ rowptr, int* __restrict__ cursor,
                               int* __restrict__ col) {
  int r = blockIdx.y;
  int e = blockIdx.x * 256 + threadIdx.x;
  if (e < kE) {
    int d = dst[r * kE + e];
    int p = atomicAdd(&cursor[r * kN + d], 1);
    col[r * kE + rowptr[r * (kN + 1) + d] + p] = src[r * kE + e];
  }
}

// ---- fused edge softmax + aggregation over all relations; vv out as hi/lo pair ----
__global__ void gat3_kernel(const int* __restrict__ rowptr, const int* __restrict__ colidx,
                            const ushort* __restrict__ z, const float* __restrict__ elr,
                            const float* __restrict__ wsm, const float* __restrict__ cvec,
                            __bf16* __restrict__ vvhi, __bf16* __restrict__ vvlo) {
  int idx = blockIdx.x * 256 + threadIdx.x;
  if (idx >= kN * kH) return;
  int d = idx >> 4, hh = idx & 15;
  float out[kFH];
  const float* cv = cvec + (hh << 3);
#pragma unroll
  for (int f = 0; f < kFH; f++) out[f] = cv[f];
  for (int r = 0; r < kR; r++) {
    const int* rp = rowptr + r * (kN + 1);
    const int* ci = colidx + (size_t)r * kE;
    const ushort* zr = z + (size_t)r * kN * kHID;
    float erd = elr[((size_t)d << 7) + r * 32 + (hh << 1) + 1];
    int beg = rp[d], end = rp[d + 1];
    float s = 0.f;
    float acc[kFH] = {};
    for (int p = beg; p < end; p++) {
      int sv = ci[p];
      float v = elr[((size_t)sv << 7) + r * 32 + (hh << 1)] + erd;
      v = v > 0.f ? v : 0.2f * v;
      float ex = __expf(v);   // logits O(0.1): no overflow, identical softmax
      s += ex;
      uint4 zz = *(const uint4*)(zr + ((size_t)sv << 7) + (hh << 3));
      acc[0] = fmaf(ex, __uint_as_float(zz.x << 16),         acc[0]);
      acc[1] = fmaf(ex, __uint_as_float(zz.x & 0xffff0000u), acc[1]);
      acc[2] = fmaf(ex, __uint_as_float(zz.y << 16),         acc[2]);
      acc[3] = fmaf(ex, __uint_as_float(zz.y & 0xffff0000u), acc[3]);
      acc[4] = fmaf(ex, __uint_as_float(zz.z << 16),         acc[4]);
      acc[5] = fmaf(ex, __uint_as_float(zz.z & 0xffff0000u), acc[5]);
      acc[6] = fmaf(ex, __uint_as_float(zz.w << 16),         acc[6]);
      acc[7] = fmaf(ex, __uint_as_float(zz.w & 0xffff0000u), acc[7]);
    }
    float inv = s > 0.f ? 1.f / s : 0.f;
    const float* wp = wsm + r * kHID + (hh << 3);
#pragma unroll
    for (int f = 0; f < kFH; f++) out[f] = fmaf(wp[f] * inv, acc[f], out[f]);
  }
  union { __bf16 b[8]; uint4 u; } uh, ul;
#pragma unroll
  for (int f = 0; f < kFH; f++) {
    uh.b[f] = (__bf16)out[f];
    ul.b[f] = (__bf16)(out[f] - (float)uh.b[f]);
  }
  *(uint4*)&vvhi[((size_t)d << 7) + (hh << 3)] = uh.u;
  *(uint4*)&vvlo[((size_t)d << 7) + (hh << 3)] = ul.u;
}

// ---- relation softmax weights + folded bias ----
__global__ void wsoft_kernel(const float* __restrict__ p, const float* __restrict__ b,
                             float* __restrict__ w, float* __restrict__ c) {
  int f = threadIdx.x;  // 128 threads
  float p0 = p[f], p1 = p[kHID + f], p2 = p[2 * kHID + f];
  float mx = fmaxf(p0, fmaxf(p1, p2));
  float e0 = __expf(p0 - mx), e1 = __expf(p1 - mx), e2 = __expf(p2 - mx);
  float s = e0 + e1 + e2;
  float w0 = e0 / s, w1 = e1 / s, w2 = e2 / s;
  w[f] = w0; w[kHID + f] = w1; w[2 * kHID + f] = w2;
  c[f] = w0 * b[f] + w1 * b[kHID + f] + w2 * b[2 * kHID + f];
}

// ---- final gemv with fused BN+ReLU on input ----
__global__ void gemv_out_kernel(const float* __restrict__ A, const float* __restrict__ sc,
                                const float* __restrict__ sh, const float* __restrict__ w,
                                const float* __restrict__ b, float* __restrict__ out,
                                int n, int k) {
  int i = blockIdx.x * 256 + threadIdx.x;
  if (i >= n) return;
  const float4* a = (const float4*)(A + (size_t)i * k);
  float acc = b[0];
  for (int j4 = 0; j4 < k / 4; j4++) {
    float4 x = a[j4];
    int c = j4 * 4;
    acc = fmaf(fmaxf(fmaf(x.x, sc[c],     sh[c]),     0.f), w[c],     acc);
    acc = fmaf(fmaxf(fmaf(x.y, sc[c + 1], sh[c + 1]), 0.f), w[c + 1], acc);
    acc = fmaf(fmaxf(fmaf(x.z, sc[c + 2], sh[c + 2]), 0.f), w[c + 2], acc);
    acc = fmaf(fmaxf(fmaf(x.w, sc[c + 3], sh[c + 3]), 0.f), w[c + 3], acc);
  }
  out[i] = acc;
}

extern "C" void kernel_launch(void* const* d_in, const int* in_sizes, int n_in,
                              void* d_out, int out_size, void* d_ws, size_t ws_size,
                              hipStream_t stream) {
  const float* inputs = (const float*)d_in[0];
  const int*   src    = (const int*)d_in[1];
  const int*   dst    = (const int*)d_in[2];
  const float* e1_W   = (const float*)d_in[3];
  const float* e1_b   = (const float*)d_in[4];
  const float* e_g    = (const float*)d_in[5];
  const float* e_bt   = (const float*)d_in[6];
  const float* e2_W   = (const float*)d_in[7];
  const float* e2_b   = (const float*)d_in[8];
  const float* gat_W  = (const float*)d_in[9];
  const float* gat_al = (const float*)d_in[10];
  const float* gat_ar = (const float*)d_in[11];
  const float* gat_b  = (const float*)d_in[12];
  const float* attn_p = (const float*)d_in[13];
  const float* m1_W   = (const float*)d_in[14];
  const float* m1_b   = (const float*)d_in[15];
  const float* m_g    = (const float*)d_in[16];
  const float* m_bt   = (const float*)d_in[17];
  const float* m2_W   = (const float*)d_in[18];
  const float* m2_b   = (const float*)d_in[19];
  const float* d1_W   = (const float*)d_in[20];
  const float* d1_b   = (const float*)d_in[21];
  const float* d_g    = (const float*)d_in[22];
  const float* d_bt   = (const float*)d_in[23];
  const float* d2_W   = (const float*)d_in[24];
  const float* d2_b   = (const float*)d_in[25];

  float* ws = (float*)d_ws;
  size_t o = 0;
  float*  h     = ws + o; o += (size_t)kN * kHID;
  float*  bufA  = ws + o; o += (size_t)kN * kHID;
  float*  elr   = ws + o; o += (size_t)kN * kHID;
  __bf16* hhi   = (__bf16*)(ws + o); o += (size_t)kN * kHID / 2;
  __bf16* hlo   = (__bf16*)(ws + o); o += (size_t)kN * kHID / 2;
  __bf16* sbh   = (__bf16*)(ws + o); o += (size_t)kN * kHID / 2;
  __bf16* sbl   = (__bf16*)(ws + o); o += (size_t)kN * kHID / 2;
  __bf16* vvhi  = (__bf16*)(ws + o); o += (size_t)kN * kHID / 2;
  __bf16* vvlo  = (__bf16*)(ws + o); o += (size_t)kN * kHID / 2;
  __bf16* inhi  = (__bf16*)(ws + o); o += (size_t)kN * kIN / 2;
  __bf16* inlo  = (__bf16*)(ws + o); o += (size_t)kN * kIN / 2;
  ushort* z     = (ushort*)(ws + o); o += (size_t)kR * kN * kHID / 2;
  __bf16* wt    = (__bf16*)(ws + o); o += 327680 / 2;
  float*  elW   = ws + o; o += 2 * kHID * kHID;
  float*  bnacc = ws + o; o += 4 * kHID;          // [sums][sumsqs][sc][sh]
  float*  wsm   = ws + o; o += kR * kHID;
  float*  cvec  = ws + o; o += kHID;
  int* rowptr   = (int*)(ws + o); o += (size_t)kR * (kN + 1);
  int* colidx   = (int*)(ws + o); o += (size_t)kR * kE;
  int* degcur   = (int*)(ws + o); o += (size_t)6 * kN;
  int* bsum     = (int*)(ws + o); o += kR * kSB;
  (void)ws_size; (void)in_sizes; (void)n_in; (void)out_size;

  int* deg    = degcur;
  int* cursor = degcur + 3 * kN;

  // wt offsets (in __bf16 elements; each matrix stores hi[m][k] then lo[m][k])
  const long kWE1 = 0, kWE2 = 16384, kWZ = 49152;
  const long kWM1_0 = 245760, kWM1_1 = 262144, kWM2_0 = 278528, kWM2_1 = 294912, kWD1 = 311296;

  auto nb = [](long t) { return (int)((t + 255) / 256); };
  const long NHh = (long)kN * kH;
  const dim3 gE(nb(kE), kR);
  const dim3 gS(kSB, kR);
  const dim3 gT128((kN + 127) / 128, 2);                 // tgemm m=128
  const dim3 gM128((kN + 127) / 128, 2, 1);              // mgemm m=128
  const dim3 gM64((kN + 127) / 128, 1, 1);               // mgemm m=64
  const dim3 gMZ((kN + 127) / 128, 2, kR);               // mgemm z batched
  const float invn = 1.0f / kN;
  float* F0 = nullptr; const float* cF0 = nullptr; const __bf16* bF0 = nullptr;
  float* sc = bnacc + 2 * kHID; float* sh = bnacc + 3 * kHID;

  // ---- CSR build ----
  hipMemsetAsync(degcur, 0, (size_t)6 * kN * sizeof(int), stream);
  hist_kernel<<<gE, 256, 0, stream>>>(dst, deg);
  bsum_kernel<<<gS, 256, 0, stream>>>(deg, bsum);
  bscan_kernel<<<1, 256, 0, stream>>>(bsum);
  scan2_kernel<<<gS, 256, 0, stream>>>(deg, bsum, rowptr);
  scatter_kernel<<<gE, 256, 0, stream>>>(src, dst, rowptr, cursor, colidx);

  // ---- weight prep ----
  WDescs wd;
  wd.d[0] = {e1_W, kWE1, kIN, kHID};
  wd.d[1] = {e2_W, kWE2, kHID, kHID};
  for (int i = 0; i < 6; i++) wd.d[2 + i] = {gat_W + (size_t)i * 16384, kWZ + (long)i * 32768, kHID, kHID};
  wd.d[8]  = {m1_W,        kWM1_0, kHID, kHD2};
  wd.d[9]  = {m1_W + 8192, kWM1_1, kHID, kHD2};
  wd.d[10] = {m2_W,        kWM2_0, kHD2, kHID};
  wd.d[11] = {m2_W + 8192, kWM2_1, kHD2, kHID};
  wd.d[12] = {d1_W,        kWD1,   kHID, kHD2};
  wprep_kernel<<<dim3(64, 13), 256, 0, stream>>>(wd, wt);
  elw_kernel<<<128, 256, 0, stream>>>(gat_W, gat_al, gat_ar, elW);
  split_kernel<<<nb((long)kN * kIN / 4), 256, 0, stream>>>(inputs, cF0, cF0, inhi, inlo,
                                                           kN * kIN / 4, kIN);

  // ---- embed MLP (skip=True) ----
  hipMemsetAsync(bnacc, 0, 2 * kHID * sizeof(float), stream);
  mgemm_kernel<<<gM128, 256, 0, stream>>>(inhi, inlo, wt + kWE1, e1_b, cF0, bF0, bF0,
                                          bnacc, bufA, nullptr, nullptr, kN, kIN, kHID, 0, 0);
  bnfold_kernel<<<1, kHID, 0, stream>>>(bnacc, e_g, e_bt, sc, sh, kHID, invn);
  split_kernel<<<nb((long)kN * kHID / 4), 256, 0, stream>>>(bufA, sc, sh, sbh, sbl,
                                                            kN * kHID / 4, kHID);
  mgemm_kernel<<<gM128, 256, 0, stream>>>(sbh, sbl, wt + kWE2, e2_b, cF0, sbh, sbl,
                                          F0, h, hhi, hlo, kN, kHID, kHID, 0, 0);

  for (int l = 0; l < kL; l++) {
    wsoft_kernel<<<1, kHID, 0, stream>>>(attn_p + (size_t)l * kR * kHID,
                                         gat_b + (size_t)l * kR * kHID, wsm, cvec);
    tgemm_kernel<<<gT128, 256, 0, stream>>>(h, elW + (size_t)l * kHID * kHID, elr, kN, kHID, kHID);
    mgemm_kernel<<<gMZ, 256, 0, stream>>>(hhi, hlo, wt + kWZ + (long)l * 3 * 32768, cF0, cF0,
                                          bF0, bF0, F0, F0, (__bf16*)z, nullptr,
                                          kN, kHID, kHID, 32768, (long)kN * kHID);
    gat3_kernel<<<nb(NHh), 256, 0, stream>>>(rowptr, colidx, z, elr, wsm, cvec, vvhi, vvlo);
    hipMemsetAsync(bnacc, 0, 2 * kHD2 * sizeof(float), stream);
    mgemm_kernel<<<gM64, 256, 0, stream>>>(vvhi, vvlo, wt + (l ? kWM1_1 : kWM1_0),
                                           m1_b + (size_t)l * kHD2, cF0, bF0, bF0,
                                           bnacc, bufA, nullptr, nullptr, kN, kHID, kHD2, 0, 0);
    bnfold_kernel<<<1, kHD2, 0, stream>>>(bnacc, m_g + (size_t)l * kHD2, m_bt + (size_t)l * kHD2,
                                          sc, sh, kHD2, invn);
    split_kernel<<<nb((long)kN * kHD2 / 4), 256, 0, stream>>>(bufA, sc, sh, sbh, sbl,
                                                              kN * kHD2 / 4, kHD2);
    mgemm_kernel<<<gM128, 256, 0, stream>>>(sbh, sbl, wt + (l ? kWM2_1 : kWM2_0),
                                            m2_b + (size_t)l * kHID, h, bF0, bF0,
                                            F0, h, hhi, hlo, kN, kHD2, kHID, 0, 0);
  }

  // ---- decode MLP ----
  hipMemsetAsync(bnacc, 0, 2 * kHD2 * sizeof(float), stream);
  mgemm_kernel<<<gM64, 256, 0, stream>>>(hhi, hlo, wt + kWD1, d1_b, cF0, bF0, bF0,
                                         bnacc, bufA, nullptr, nullptr, kN, kHID, kHD2, 0, 0);
  bnfold_kernel<<<1, kHD2, 0, stream>>>(bnacc, d_g, d_bt, sc, sh, kHD2, invn);
  gemv_out_kernel<<<nb(kN), 256, 0, stream>>>(bufA, sc, sh, d2_W, d2_b, (float*)d_out, kN, kHD2);
}

// Round 7
// 331.622 us; speedup vs baseline: 13.6104x; 1.1652x over previous
//
#include <hip/hip_runtime.h>
#include <math.h>

// ---- problem constants ----
constexpr int kN   = 20000;
constexpr int kE   = 160000;
constexpr int kR   = 3;
constexpr int kL   = 2;
constexpr int kIN  = 64;
constexpr int kHID = 128;
constexpr int kH   = 16;
constexpr int kFH  = 8;
constexpr int kHD2 = 64;
constexpr int kSB  = (kN + 255) / 256;   // scan blocks per relation = 79

typedef __bf16 bf16x8 __attribute__((ext_vector_type(8)));
typedef float  f32x4  __attribute__((ext_vector_type(4)));

__device__ __forceinline__ bf16x8 ldfrag(const __bf16* p) {
  return __builtin_bit_cast(bf16x8, *(const uint4*)p);
}
__device__ __forceinline__ f32x4 MF(bf16x8 a, bf16x8 b, f32x4 c) {
  return __builtin_amdgcn_mfma_f32_16x16x32_bf16(a, b, c, 0, 0, 0);
}

// load 8 f32, optional BN+ReLU, split to bf16 hi/lo fragments in-register
__device__ __forceinline__ void splitrow(const float* __restrict__ rowbase, int koff,
                                         bool bn, const float* scS, const float* shS,
                                         bf16x8& hi, bf16x8& lo) {
  float4 xa = *(const float4*)(rowbase + koff);
  float4 xb = *(const float4*)(rowbase + koff + 4);
  float x[8] = {xa.x, xa.y, xa.z, xa.w, xb.x, xb.y, xb.z, xb.w};
  union { __bf16 b[8]; bf16x8 v; } uh, ul;
#pragma unroll
  for (int e = 0; e < 8; e++) {
    float y = x[e];
    if (bn) y = fmaxf(fmaf(y, scS[koff + e], shS[koff + e]), 0.f);
    __bf16 hb = (__bf16)y;
    uh.b[e] = hb;
    ul.b[e] = (__bf16)(y - (float)hb);
  }
  hi = uh.v; lo = ul.v;
}

// ============================================================================
// MFMA GEMM, 3-pass bf16 split (~f32 precision): C = [BN+ReLU?](A) @ W (+bias)(+res)
// A f32 [n][k]; W transposed+split: WT[m][k] hi then lo.
// BM=128 (4 waves x 32 rows), BN=64 (4 col-frags/wave).
// resmode: 0 none, 1 plain f32 res, 2 res = max(resf*sc+sh,0) (needs k==m)
// Optional: bnstat/bng/bnbt -> A-side BN scale/shift derived in prologue
//           statS -> output column sums/sumsqs; Cf f32 out; Chi bf16 out
//           alb/arb/elout -> GAT el/er logits from exact f32 acc (shfl reduce)
// ============================================================================
__global__ __launch_bounds__(256) void mgemm_kernel(
    const float* __restrict__ A, const __bf16* __restrict__ WT,
    const float* __restrict__ bias, const float* __restrict__ resf, int resmode,
    const float* __restrict__ bnstat, const float* __restrict__ bng,
    const float* __restrict__ bnbt, float invn,
    float* __restrict__ statS,
    float* __restrict__ Cf, __bf16* __restrict__ Chi,
    const float* __restrict__ alb, const float* __restrict__ arb,
    float* __restrict__ elout,
    int n, int k, int m, long wstride, long cstride) {
  __shared__ __bf16 Bh[64][136];   // +8 pad -> conflict-free frag reads
  __shared__ __bf16 Bl[64][136];
  __shared__ float scS[128], shS[128];
  const int t  = threadIdx.x;
  const int w  = t >> 6;
  const int l  = t & 63;
  const int lr = l & 15;
  const int lg = l >> 4;
  const int rb = blockIdx.x * 128 + w * 32;
  const int c0 = blockIdx.y * 64;
  const __bf16* Whi = WT + (size_t)blockIdx.z * wstride;
  const __bf16* Wlo = Whi + (size_t)k * m;
  if (Chi) Chi += (size_t)blockIdx.z * cstride;
  const float* al = alb ? alb + blockIdx.z * kHID : nullptr;
  const float* ar = arb ? arb + blockIdx.z * kHID : nullptr;
  float* elo = elout ? elout + blockIdx.z * 32 : nullptr;

  const bool bn = bnstat != nullptr;
  if (bn && t < k) {
    float mu  = bnstat[t] * invn;
    float var = bnstat[k + t] * invn - mu * mu;
    float s = bng[t] * rsqrtf(var + 1e-5f);
    scS[t] = s; shS[t] = bnbt[t] - mu * s;
  }
  const int kseg = k >> 3;
  for (int idx = t; idx < 64 * kseg; idx += 256) {
    int col = idx / kseg, seg = idx - col * kseg;
    *(uint4*)&Bh[col][seg * 8] = *(const uint4*)&Whi[(size_t)(c0 + col) * k + seg * 8];
    *(uint4*)&Bl[col][seg * 8] = *(const uint4*)&Wlo[(size_t)(c0 + col) * k + seg * 8];
  }
  __syncthreads();

  int r0 = rb + lr;      if (r0 > n - 1) r0 = n - 1;
  int r1 = rb + 16 + lr; if (r1 > n - 1) r1 = n - 1;
  f32x4 acc[2][4] = {};

  for (int ks = 0; ks < (k >> 5); ks++) {
    const int koff = ks * 32 + lg * 8;
    bf16x8 a0h, a0l, a1h, a1l;
    splitrow(&A[(size_t)r0 * k], koff, bn, scS, shS, a0h, a0l);
    splitrow(&A[(size_t)r1 * k], koff, bn, scS, shS, a1h, a1l);
#pragma unroll
    for (int j = 0; j < 4; j++) {
      bf16x8 bh = ldfrag(&Bh[j * 16 + lr][koff]);
      bf16x8 bl = ldfrag(&Bl[j * 16 + lr][koff]);
      acc[0][j] = MF(a0h, bh, acc[0][j]);
      acc[0][j] = MF(a0l, bh, acc[0][j]);
      acc[0][j] = MF(a0h, bl, acc[0][j]);
      acc[1][j] = MF(a1h, bh, acc[1][j]);
      acc[1][j] = MF(a1l, bh, acc[1][j]);
      acc[1][j] = MF(a1h, bl, acc[1][j]);
    }
  }

  // epilogue: D element (i,j,q) -> row rb+i*16+lg*4+q, col c0+j*16+lr
  float s[4] = {}, s2[4] = {};
#pragma unroll
  for (int i = 0; i < 2; i++) {
#pragma unroll
    for (int q = 0; q < 4; q++) {
      int row = rb + i * 16 + lg * 4 + q;
      bool ok = row < n;
#pragma unroll
      for (int j = 0; j < 4; j++) {
        int col = c0 + j * 16 + lr;
        float v = acc[i][j][q];
        if (bias) v += bias[col];
        size_t off = (size_t)row * m + col;
        if (ok) {
          if (resmode == 1) v += resf[off];
          else if (resmode == 2) v += fmaxf(fmaf(resf[off], scS[col], shS[col]), 0.f);
          if (Cf) Cf[off] = v;
          if (Chi) Chi[off] = (__bf16)v;
          s[j] += v; s2[j] += v * v;
        }
      }
    }
  }
  if (statS) {
    __syncthreads();
    float* red = (float*)&Bh[0][0];   // 512 floats scratch
#pragma unroll
    for (int j = 0; j < 4; j++) {
      float a = s[j], b = s2[j];
      a += __shfl_xor(a, 16, 64); a += __shfl_xor(a, 32, 64);
      b += __shfl_xor(b, 16, 64); b += __shfl_xor(b, 32, 64);
      if (lg == 0) { red[w * 64 + j * 16 + lr] = a; red[256 + w * 64 + j * 16 + lr] = b; }
    }
    __syncthreads();
    if (t < 64) {
      float a = red[t] + red[64 + t] + red[128 + t] + red[192 + t];
      float b = red[256 + t] + red[320 + t] + red[384 + t] + red[448 + t];
      atomicAdd(&statS[c0 + t], a);
      atomicAdd(&statS[m + c0 + t], b);
    }
  }
  if (al) {
    // el/er from exact f32 acc: head hd = col>>3 spans 8 lanes (lr&7); shfl reduce.
#pragma unroll
    for (int i = 0; i < 2; i++) {
#pragma unroll
      for (int q = 0; q < 4; q++) {
        int row = rb + i * 16 + lg * 4 + q;
#pragma unroll
        for (int j = 0; j < 4; j++) {
          int col = c0 + j * 16 + lr;
          float zv = acc[i][j][q];
          float pl = zv * al[col];
          float pr = zv * ar[col];
          pl += __shfl_xor(pl, 1, 64); pl += __shfl_xor(pl, 2, 64); pl += __shfl_xor(pl, 4, 64);
          pr += __shfl_xor(pr, 1, 64); pr += __shfl_xor(pr, 2, 64); pr += __shfl_xor(pr, 4, 64);
          if ((lr & 7) == 0 && row < n) {
            int hd = col >> 3;
            elo[(size_t)row * kHID + hd * 2]     = pl;
            elo[(size_t)row * kHID + hd * 2 + 1] = pr;
          }
        }
      }
    }
  }
}

// ---- weight transpose + bf16 hi/lo split prep ----
struct WDesc { const float* src; long doff; int k, m; };
struct WDescs { WDesc d[13]; };
__global__ void wprep_kernel(WDescs ds, __bf16* __restrict__ wt) {
  WDesc dd = ds.d[blockIdx.y];
  int idx = blockIdx.x * 256 + threadIdx.x;
  if (idx >= dd.k * dd.m) return;
  int row = idx / dd.m, col = idx - row * dd.m;   // src [k][m] row-major
  float v = dd.src[idx];
  __bf16 hb = (__bf16)v;
  __bf16 lb = (__bf16)(v - (float)hb);
  wt[dd.doff + (size_t)col * dd.k + row] = hb;
  wt[dd.doff + (size_t)dd.k * dd.m + (size_t)col * dd.k + row] = lb;
}

// ---- CSR build (batched over relations via blockIdx.y) ----
__global__ void hist_kernel(const int* __restrict__ dst, int* __restrict__ deg) {
  int r = blockIdx.y;
  int e = blockIdx.x * 256 + threadIdx.x;
  if (e < kE) atomicAdd(&deg[r * kN + dst[r * kE + e]], 1);
}

__global__ void bsum_kernel(const int* __restrict__ deg, int* __restrict__ bsum) {
  int r = blockIdx.y;
  int j = blockIdx.x * 256 + threadIdx.x;
  int x = (j < kN) ? deg[r * kN + j] : 0;
  __shared__ int shm[256];
  shm[threadIdx.x] = x;
  __syncthreads();
  for (int off = 128; off > 0; off >>= 1) {
    if (threadIdx.x < off) shm[threadIdx.x] += shm[threadIdx.x + off];
    __syncthreads();
  }
  if (threadIdx.x == 0) bsum[r * kSB + blockIdx.x] = shm[0];
}

__global__ void bscan_kernel(int* __restrict__ bsum) {
  __shared__ int shm[kR * kSB];
  int t = threadIdx.x;
  for (int i = t; i < kR * kSB; i += 256) shm[i] = bsum[i];
  __syncthreads();
  if (t < kR) {
    int run = 0;
    for (int b = 0; b < kSB; b++) { int v = shm[t * kSB + b]; shm[t * kSB + b] = run; run += v; }
  }
  __syncthreads();
  for (int i = t; i < kR * kSB; i += 256) bsum[i] = shm[i];
}

__global__ void scan2_kernel(const int* __restrict__ deg, const int* __restrict__ bsum,
                             int* __restrict__ rowptr) {
  int r = blockIdx.y;
  int t = threadIdx.x;
  int j = blockIdx.x * 256 + t;
  int x = (j < kN) ? deg[r * kN + j] : 0;
  int lane = t & 63, w = t >> 6;
  int v = x;
  for (int off = 1; off < 64; off <<= 1) {
    int y = __shfl_up(v, off, 64);
    if (lane >= off) v += y;
  }
  __shared__ int wtot[4];
  if (lane == 63) wtot[w] = v;
  __syncthreads();
  int add = bsum[r * kSB + blockIdx.x];
  for (int i = 0; i < 4; i++) if (i < w) add += wtot[i];
  if (j < kN) rowptr[r * (kN + 1) + j] = add + v - x;
  if (blockIdx.x == 0 && t == 0) rowptr[r * (kN + 1) + kN] = kE;
}

__global__ void scatter_kernel(const int* __restrict__ src, const int* __restrict__ dst,
                               const int* __restrict__ rowptr, int* __restrict__ cursor,
                               int* __restrict__ col) {
  int r = blockIdx.y;
  int e = blockIdx.x * 256 + threadIdx.x;
  if (e < kE) {
    int d = dst[r * kE + e];
    int p = atomicAdd(&cursor[r * kN + d], 1);
    col[r * kE + rowptr[r * (kN + 1) + d] + p] = src[r * kE + e];
  }
}

// ---- fused relation-softmax + edge softmax + aggregation; f32 vv out ----
__global__ void gat3_kernel(const int* __restrict__ rowptr, const int* __restrict__ colidx,
                            const ushort* __restrict__ z, const float* __restrict__ elr,
                            const float* __restrict__ attn_pl, const float* __restrict__ gat_bl,
                            float* __restrict__ vv) {
  __shared__ float wsmS[kR * kHID], cvecS[kHID];
  int t = threadIdx.x;
  if (t < kHID) {
    float p0 = attn_pl[t], p1 = attn_pl[kHID + t], p2 = attn_pl[2 * kHID + t];
    float mx = fmaxf(p0, fmaxf(p1, p2));
    float e0 = __expf(p0 - mx), e1 = __expf(p1 - mx), e2 = __expf(p2 - mx);
    float si = 1.f / (e0 + e1 + e2);
    wsmS[t] = e0 * si; wsmS[kHID + t] = e1 * si; wsmS[2 * kHID + t] = e2 * si;
    cvecS[t] = (e0 * gat_bl[t] + e1 * gat_bl[kHID + t] + e2 * gat_bl[2 * kHID + t]) * si;
  }
  __syncthreads();
  int idx = blockIdx.x * 256 + t;
  if (idx >= kN * kH) return;
  int d = idx >> 4, hh = idx & 15;
  float out[kFH];
#pragma unroll
  for (int f = 0; f < kFH; f++) out[f] = cvecS[(hh << 3) + f];
  for (int r = 0; r < kR; r++) {
    const int* rp = rowptr + r * (kN + 1);
    const int* ci = colidx + (size_t)r * kE;
    const ushort* zr = z + (size_t)r * kN * kHID;
    float erd = elr[((size_t)d << 7) + r * 32 + (hh << 1) + 1];
    int beg = rp[d], end = rp[d + 1];
    float s = 0.f;
    float acc[kFH] = {};
    for (int p = beg; p < end; p++) {
      int sv = ci[p];
      float v = elr[((size_t)sv << 7) + r * 32 + (hh << 1)] + erd;
      v = v > 0.f ? v : 0.2f * v;
      float ex = __expf(v);   // logits O(0.1): no overflow, identical softmax
      s += ex;
      uint4 zz = *(const uint4*)(zr + ((size_t)sv << 7) + (hh << 3));
      acc[0] = fmaf(ex, __uint_as_float(zz.x << 16),         acc[0]);
      acc[1] = fmaf(ex, __uint_as_float(zz.x & 0xffff0000u), acc[1]);
      acc[2] = fmaf(ex, __uint_as_float(zz.y << 16),         acc[2]);
      acc[3] = fmaf(ex, __uint_as_float(zz.y & 0xffff0000u), acc[3]);
      acc[4] = fmaf(ex, __uint_as_float(zz.z << 16),         acc[4]);
      acc[5] = fmaf(ex, __uint_as_float(zz.z & 0xffff0000u), acc[5]);
      acc[6] = fmaf(ex, __uint_as_float(zz.w << 16),         acc[6]);
      acc[7] = fmaf(ex, __uint_as_float(zz.w & 0xffff0000u), acc[7]);
    }
    float inv = s > 0.f ? 1.f / s : 0.f;
    const float* wp = wsmS + r * kHID + (hh << 3);
#pragma unroll
    for (int f = 0; f < kFH; f++) out[f] = fmaf(wp[f] * inv, acc[f], out[f]);
  }
  float4* vp = (float4*)(vv + ((size_t)d << 7) + (hh << 3));
  vp[0] = make_float4(out[0], out[1], out[2], out[3]);
  vp[1] = make_float4(out[4], out[5], out[6], out[7]);
}

// ---- final gemv: BN fold from raw stats + BN+ReLU + dot, all fused ----
__global__ void gemv_out_kernel(const float* __restrict__ A, const float* __restrict__ statS,
                                const float* __restrict__ g, const float* __restrict__ bt,
                                float invn, const float* __restrict__ w,
                                const float* __restrict__ b, float* __restrict__ out,
                                int n, int k) {
  __shared__ float scS[kHD2], shS[kHD2];
  int t = threadIdx.x;
  if (t < k) {
    float mu  = statS[t] * invn;
    float var = statS[k + t] * invn - mu * mu;
    float s = g[t] * rsqrtf(var + 1e-5f);
    scS[t] = s; shS[t] = bt[t] - mu * s;
  }
  __syncthreads();
  int i = blockIdx.x * 256 + t;
  if (i >= n) return;
  const float4* a = (const float4*)(A + (size_t)i * k);
  float acc = b[0];
  for (int j4 = 0; j4 < k / 4; j4++) {
    float4 x = a[j4];
    int c = j4 * 4;
    acc = fmaf(fmaxf(fmaf(x.x, scS[c],     shS[c]),     0.f), w[c],     acc);
    acc = fmaf(fmaxf(fmaf(x.y, scS[c + 1], shS[c + 1]), 0.f), w[c + 1], acc);
    acc = fmaf(fmaxf(fmaf(x.z, scS[c + 2], shS[c + 2]), 0.f), w[c + 2], acc);
    acc = fmaf(fmaxf(fmaf(x.w, scS[c + 3], shS[c + 3]), 0.f), w[c + 3], acc);
  }
  out[i] = acc;
}

extern "C" void kernel_launch(void* const* d_in, const int* in_sizes, int n_in,
                              void* d_out, int out_size, void* d_ws, size_t ws_size,
                              hipStream_t stream) {
  const float* inputs = (const float*)d_in[0];
  const int*   src    = (const int*)d_in[1];
  const int*   dst    = (const int*)d_in[2];
  const float* e1_W   = (const float*)d_in[3];
  const float* e1_b   = (const float*)d_in[4];
  const float* e_g    = (const float*)d_in[5];
  const float* e_bt   = (const float*)d_in[6];
  const float* e2_W   = (const float*)d_in[7];
  const float* e2_b   = (const float*)d_in[8];
  const float* gat_W  = (const float*)d_in[9];
  const float* gat_al = (const float*)d_in[10];
  const float* gat_ar = (const float*)d_in[11];
  const float* gat_b  = (const float*)d_in[12];
  const float* attn_p = (const float*)d_in[13];
  const float* m1_W   = (const float*)d_in[14];
  const float* m1_b   = (const float*)d_in[15];
  const float* m_g    = (const float*)d_in[16];
  const float* m_bt   = (const float*)d_in[17];
  const float* m2_W   = (const float*)d_in[18];
  const float* m2_b   = (const float*)d_in[19];
  const float* d1_W   = (const float*)d_in[20];
  const float* d1_b   = (const float*)d_in[21];
  const float* d_g    = (const float*)d_in[22];
  const float* d_bt   = (const float*)d_in[23];
  const float* d2_W   = (const float*)d_in[24];
  const float* d2_b   = (const float*)d_in[25];

  float* ws = (float*)d_ws;
  size_t o = 0;
  float*  h     = ws + o; o += (size_t)kN * kHID;
  float*  bufA  = ws + o; o += (size_t)kN * kHID;
  float*  elr   = ws + o; o += (size_t)kN * kHID;
  float*  vv    = ws + o; o += (size_t)kN * kHID;
  __bf16* z     = (__bf16*)(ws + o); o += (size_t)kR * kN * kHID / 2;
  __bf16* wt    = (__bf16*)(ws + o); o += 327680 / 2;
  float*  stats = ws + o; o += 640;   // [e1:256][m1_l0:128][m1_l1:128][d1:128]
  int* rowptr   = (int*)(ws + o); o += (size_t)kR * (kN + 1);
  int* colidx   = (int*)(ws + o); o += (size_t)kR * kE;
  int* degcur   = (int*)(ws + o); o += (size_t)6 * kN;
  int* bsum     = (int*)(ws + o); o += kR * kSB;
  (void)ws_size; (void)in_sizes; (void)n_in; (void)out_size;

  int* deg    = degcur;
  int* cursor = degcur + 3 * kN;
  float* stat_e1 = stats;
  float* stat_m1[2] = {stats + 256, stats + 384};
  float* stat_d1 = stats + 512;

  // wt offsets (__bf16 elements; each matrix: hi[m][k] then lo[m][k])
  const long kWE1 = 0, kWE2 = 16384, kWZ = 49152;
  const long kWM1_0 = 245760, kWM1_1 = 262144, kWM2_0 = 278528, kWM2_1 = 294912, kWD1 = 311296;

  auto nb = [](long t) { return (int)((t + 255) / 256); };
  const long NHh = (long)kN * kH;
  const dim3 gE(nb(kE), kR);
  const dim3 gS(kSB, kR);
  const dim3 gM128((kN + 127) / 128, 2, 1);
  const dim3 gM64((kN + 127) / 128, 1, 1);
  const dim3 gMZ((kN + 127) / 128, 2, kR);
  const float invn = 1.0f / kN;
  float* F0 = nullptr; const float* cF0 = nullptr;

  // ---- CSR build ----
  hipMemsetAsync(degcur, 0, (size_t)6 * kN * sizeof(int), stream);
  hist_kernel<<<gE, 256, 0, stream>>>(dst, deg);
  bsum_kernel<<<gS, 256, 0, stream>>>(deg, bsum);
  bscan_kernel<<<1, 256, 0, stream>>>(bsum);
  scan2_kernel<<<gS, 256, 0, stream>>>(deg, bsum, rowptr);
  scatter_kernel<<<gE, 256, 0, stream>>>(src, dst, rowptr, cursor, colidx);

  // ---- weight prep + stat zero ----
  WDescs wd;
  wd.d[0] = {e1_W, kWE1, kIN, kHID};
  wd.d[1] = {e2_W, kWE2, kHID, kHID};
  for (int i = 0; i < 6; i++) wd.d[2 + i] = {gat_W + (size_t)i * 16384, kWZ + (long)i * 32768, kHID, kHID};
  wd.d[8]  = {m1_W,        kWM1_0, kHID, kHD2};
  wd.d[9]  = {m1_W + 8192, kWM1_1, kHID, kHD2};
  wd.d[10] = {m2_W,        kWM2_0, kHD2, kHID};
  wd.d[11] = {m2_W + 8192, kWM2_1, kHD2, kHID};
  wd.d[12] = {d1_W,        kWD1,   kHID, kHD2};
  wprep_kernel<<<dim3(64, 13), 256, 0, stream>>>(wd, wt);
  hipMemsetAsync(stats, 0, 640 * sizeof(float), stream);

  // ---- embed MLP (skip=True): e1 -> stats; e2 with in-register BN+ReLU + res ----
  mgemm_kernel<<<gM128, 256, 0, stream>>>(inputs, wt + kWE1, e1_b, cF0, 0,
                                          cF0, cF0, cF0, invn, stat_e1, bufA, nullptr,
                                          cF0, cF0, F0, kN, kIN, kHID, 0, 0);
  mgemm_kernel<<<gM128, 256, 0, stream>>>(bufA, wt + kWE2, e2_b, bufA, 2,
                                          stat_e1, e_g, e_bt, invn, F0, h, nullptr,
                                          cF0, cF0, F0, kN, kHID, kHID, 0, 0);

  for (int l = 0; l < kL; l++) {
    // z projections (x3 relations) with fused el/er epilogue
    mgemm_kernel<<<gMZ, 256, 0, stream>>>(h, wt + kWZ + (long)l * 3 * 32768, cF0, cF0, 0,
                                          cF0, cF0, cF0, invn, F0, F0, z,
                                          gat_al + (size_t)l * kR * kHID,
                                          gat_ar + (size_t)l * kR * kHID, elr,
                                          kN, kHID, kHID, 32768, (long)kN * kHID);
    gat3_kernel<<<nb(NHh), 256, 0, stream>>>(rowptr, colidx, (const ushort*)z, elr,
                                             attn_p + (size_t)l * kR * kHID,
                                             gat_b + (size_t)l * kR * kHID, vv);
    mgemm_kernel<<<gM64, 256, 0, stream>>>(vv, wt + (l ? kWM1_1 : kWM1_0),
                                           m1_b + (size_t)l * kHD2, cF0, 0,
                                           cF0, cF0, cF0, invn, stat_m1[l], bufA, nullptr,
                                           cF0, cF0, F0, kN, kHID, kHD2, 0, 0);
    mgemm_kernel<<<gM128, 256, 0, stream>>>(bufA, wt + (l ? kWM2_1 : kWM2_0),
                                            m2_b + (size_t)l * kHID, h, 1,
                                            stat_m1[l], m_g + (size_t)l * kHD2,
                                            m_bt + (size_t)l * kHD2, invn, F0, h, nullptr,
                                            cF0, cF0, F0, kN, kHD2, kHID, 0, 0);
  }

  // ---- decode MLP ----
  mgemm_kernel<<<gM64, 256, 0, stream>>>(h, wt + kWD1, d1_b, cF0, 0,
                                         cF0, cF0, cF0, invn, stat_d1, bufA, nullptr,
                                         cF0, cF0, F0, kN, kHID, kHD2, 0, 0);
  gemv_out_kernel<<<nb(kN), 256, 0, stream>>>(bufA, stat_d1, d_g, d_bt, invn,
                                              d2_W, d2_b, (float*)d_out, kN, kHD2);
}